// Round 3
// baseline (2316.021 us; speedup 1.0000x reference)
//
#include <hip/hip_runtime.h>
#include <math.h>

#define NP 401            // tokens incl. CLS (400 patches, side=20, add=0)
#define DIM 512
#define LN_EPS 1e-5f
#define ATT_SCALE 0.125f
#define CPB_M 4096        // angle-table resolution (interp err ~2e-5 << tol)
#define TSTRIDE (CPB_M + 64)
#define PQS (401L * 1536) // layer-1 qkv partial slice stride
#define PKS (401L * 1024) // layer-2 kv partial slice stride
#define PVS (401L * 512)  // pv / proj partial slice stride

// Persistent-kernel grid: 768 blocks x 256 thr = 3 blocks/CU.
// Co-residency guaranteed: __launch_bounds__(256,3) caps VGPR at 170 (have
// ~84); LDS 34.9KB*3 = 104.7KB <= 160KB. Software grid barrier is therefore
// deadlock-free independent of dispatch order (G16).
#define GRID 768
#define FSTRIDE 32        // flag spacing: 32 u32 = 128B (one cache line)

// ---------------------------------------------------------------------------
// Contention-free grid barrier. NO atomic RMWs (round-2 lesson: 512 ACQ_REL
// fetch_adds on one line serialize at ~170ns each => ~85us/barrier).
// Arrival: per-block flag on its own 128B line (release store, monotone gen).
// Aggregation: block 0's 256 threads poll 3 flags each (pipelined loads).
// Release: single store to gen word; everyone else polls it.
// ---------------------------------------------------------------------------
__device__ __forceinline__ void gsync(unsigned* gen, unsigned* flags,
                                      unsigned target)
{
    __threadfence();          // release: every thread flushes its own writes
    __syncthreads();
    const int tid = threadIdx.x;
    if (blockIdx.x == 0) {
        for (int i = tid; i < GRID; i += 256) {
            if (i == 0) continue;
            while (__hip_atomic_load(&flags[i * FSTRIDE], __ATOMIC_RELAXED,
                                     __HIP_MEMORY_SCOPE_AGENT) < target)
                __builtin_amdgcn_s_sleep(1);
        }
        __syncthreads();      // all flags seen
        if (tid == 0)
            __hip_atomic_store(gen, target, __ATOMIC_RELEASE,
                               __HIP_MEMORY_SCOPE_AGENT);
    } else {
        if (tid == 0) {
            __hip_atomic_store(&flags[blockIdx.x * FSTRIDE], target,
                               __ATOMIC_RELEASE, __HIP_MEMORY_SCOPE_AGENT);
            while (__hip_atomic_load(gen, __ATOMIC_ACQUIRE,
                                     __HIP_MEMORY_SCOPE_AGENT) < target)
                __builtin_amdgcn_s_sleep(8);
        }
        __syncthreads();
    }
    __threadfence();          // acquire: drop stale cached lines
}

// ---------------------------------------------------------------------------
// 64x64-tile GEMM body: 256 thr, 4x4 micro-tile, K-chunk 16, register
// double-buffered staging via caller-supplied loaders. (unchanged)
// ---------------------------------------------------------------------------
template<bool TB, typename LA, typename LB>
__device__ __forceinline__ void gemm64(
    int kBeg, int kEnd, int tid,
    float (*as)[68], float (*bs)[68], float (&acc)[4][4],
    LA&& loadA, LB&& loadB)
{
    float aR[4], bR[4];
    loadA(kBeg, aR);
    loadB(kBeg, bR);
    for (int k0 = kBeg; k0 < kEnd; k0 += 16) {
        const int arow = tid >> 2, aq = tid & 3;
        as[aq * 4 + 0][arow] = aR[0];
        as[aq * 4 + 1][arow] = aR[1];
        as[aq * 4 + 2][arow] = aR[2];
        as[aq * 4 + 3][arow] = aR[3];
        if (!TB) {
            *(float4*)&bs[tid >> 4][(tid & 15) * 4] =
                make_float4(bR[0], bR[1], bR[2], bR[3]);
        } else {
            bs[aq * 4 + 0][arow] = bR[0];
            bs[aq * 4 + 1][arow] = bR[1];
            bs[aq * 4 + 2][arow] = bR[2];
            bs[aq * 4 + 3][arow] = bR[3];
        }
        __syncthreads();
        float nA[4] = {0.f,0.f,0.f,0.f}, nB[4] = {0.f,0.f,0.f,0.f};
        if (k0 + 16 < kEnd) { loadA(k0 + 16, nA); loadB(k0 + 16, nB); }
        const int tx = tid & 15, ty = tid >> 4;
        #pragma unroll
        for (int kk = 0; kk < 16; ++kk) {
            float4 a4 = *(const float4*)&as[kk][ty * 4];
            float4 b4 = *(const float4*)&bs[kk][tx * 4];
            float av[4] = {a4.x, a4.y, a4.z, a4.w};
            float bv[4] = {b4.x, b4.y, b4.z, b4.w};
            #pragma unroll
            for (int r = 0; r < 4; ++r)
                #pragma unroll
                for (int c = 0; c < 4; ++c)
                    acc[r][c] = fmaf(av[r], bv[c], acc[r][c]);
        }
        __syncthreads();
        #pragma unroll
        for (int j = 0; j < 4; ++j) { aR[j] = nA[j]; bR[j] = nB[j]; }
    }
}

// ---------------------------------------------------------------------------
// Phase bodies (verbatim from round 2 except flash LDS aliasing)
// ---------------------------------------------------------------------------
__device__ __forceinline__ void gemm_split_body(
    float (*as)[68], float (*bs)[68], int tid,
    int m0, int n0, int sk,
    const float* A, int lda, const float* B, int ldb,
    float* Pout, int ldc, long slice, int M, int K, int skN)
{
    const int KS = ((K + skN * 16 - 1) / (skN * 16)) * 16;
    const int kBeg = sk * KS;
    const int kEnd = (kBeg + KS < K) ? kBeg + KS : K;
    float acc[4][4] = {};

    auto loadA = [&](int k0, float r[4]) {
        r[0] = r[1] = r[2] = r[3] = 0.f;
        int gm = m0 + (tid >> 2);
        if (gm >= M) return;
        int gk = k0 + (tid & 3) * 4;
        const float* p = A + (long)gm * lda + gk;
        if (gk + 3 < kEnd) {
            float4 v = *(const float4*)p;
            r[0] = v.x; r[1] = v.y; r[2] = v.z; r[3] = v.w;
        } else {
            #pragma unroll
            for (int j = 0; j < 4; ++j) if (gk + j < kEnd) r[j] = p[j];
        }
    };
    auto loadB = [&](int k0, float r[4]) {
        r[0] = r[1] = r[2] = r[3] = 0.f;
        int gk = k0 + (tid >> 4);
        if (gk >= kEnd) return;
        int gn = n0 + (tid & 15) * 4;
        const float* p = B + (long)gk * ldb + gn;
        float4 v = *(const float4*)p;
        r[0] = v.x; r[1] = v.y; r[2] = v.z; r[3] = v.w;
    };
    if (kBeg < kEnd)
        gemm64<false>(kBeg, kEnd, tid, as, bs, acc, loadA, loadB);

    float* C = Pout + (long)sk * slice;
    const int tx = tid & 15, ty = tid >> 4;
    #pragma unroll
    for (int r = 0; r < 4; ++r) {
        int m = m0 + ty * 4 + r;
        if (m >= M) continue;
        *(float4*)&C[(long)m * ldc + n0 + tx * 4] =
            make_float4(acc[r][0], acc[r][1], acc[r][2], acc[r][3]);
    }
}

__device__ __forceinline__ void reduce_body(
    int vb, int tid, const float* P, long slice, int skN,
    const float* bias, float* out, int total, int N)
{
    int idx = (vb * 256 + tid) * 4;
    if (idx >= total) return;
    float4 s = *(const float4*)(P + idx);
    for (int k = 1; k < skN; ++k) {
        float4 p = *(const float4*)(P + (long)k * slice + idx);
        s.x += p.x; s.y += p.y; s.z += p.z; s.w += p.w;
    }
    if (bias) {
        const float4 b = *(const float4*)(bias + (idx % N));
        s.x += b.x; s.y += b.y; s.z += b.z; s.w += b.w;
    }
    *(float4*)(out + idx) = s;
}

// flash: pT aliases as/bs (dead after gemm64's final __syncthreads);
// vs sits above. LDS footprint = 8704 floats total for the whole kernel.
__device__ __forceinline__ void flash_body(
    float (*as)[68], float (*bs)[68], float (*pT)[68], float (*vs)[68],
    int tid, int m0, int nb, int h,
    const float* qkv, const int* pm, const float* pf, const float* T,
    float* PO, float* Pml)
{
    const int n0 = nb * 64;
    float acc[4][4] = {};

    float vreg[4][4];
    {
        int key = n0 + (tid >> 2);
        int d0 = (tid & 3) * 16;
        if (key <= 400) {
            const float* p = qkv + (long)key * 1536 + 1024 + h * 64 + d0;
            #pragma unroll
            for (int i = 0; i < 4; ++i) {
                float4 v = *(const float4*)(p + i * 4);
                vreg[i][0] = v.x; vreg[i][1] = v.y;
                vreg[i][2] = v.z; vreg[i][3] = v.w;
            }
        } else {
            #pragma unroll
            for (int i = 0; i < 4; ++i)
                vreg[i][0] = vreg[i][1] = vreg[i][2] = vreg[i][3] = 0.f;
        }
    }

    auto loadQ = [&](int k0, float r[4]) {
        int gm = m0 + (tid >> 2);
        if (gm > 400) { r[0]=r[1]=r[2]=r[3]=0.f; return; }
        int gk = k0 + (tid & 3) * 4;
        float4 v = *(const float4*)(qkv + (long)gm * 1536 + h * 64 + gk);
        r[0]=v.x; r[1]=v.y; r[2]=v.z; r[3]=v.w;
    };
    auto loadK = [&](int k0, float r[4]) {
        int gn = n0 + (tid >> 2);
        if (gn > 400) { r[0]=r[1]=r[2]=r[3]=0.f; return; }
        int gk = k0 + (tid & 3) * 4;
        float4 v = *(const float4*)(qkv + (long)gn * 1536 + 512 + h * 64 + gk);
        r[0]=v.x; r[1]=v.y; r[2]=v.z; r[3]=v.w;
    };
    gemm64<true>(0, 64, tid, as, bs, acc, loadQ, loadK);
    // all waves past gemm64's final __syncthreads: as/bs dead, pT/vs writable

    {
        int key = tid >> 2, d0 = (tid & 3) * 16;
        #pragma unroll
        for (int i = 0; i < 4; ++i)
            *(float4*)&vs[key][d0 + i * 4] =
                make_float4(vreg[i][0], vreg[i][1], vreg[i][2], vreg[i][3]);
    }

    const int tx = tid & 15, ty = tid >> 4;
    const float* Tt = T + (long)h * TSTRIDE;
    float p[4][4];
    #pragma unroll
    for (int r = 0; r < 4; ++r) {
        int i = m0 + ty * 4 + r;
        float sv[4];
        #pragma unroll
        for (int c = 0; c < 4; ++c) {
            int j = n0 + tx * 4 + c;
            if (i <= 400 && j <= 400) {
                int id = i * 416 + j;
                int mm = pm[id];
                float fr = pf[id];
                float t0 = Tt[mm], t1 = Tt[mm + 1];
                sv[c] = fmaf(acc[r][c], ATT_SCALE, fmaf(fr, t1 - t0, t0));
            } else {
                sv[c] = -INFINITY;
            }
        }
        float cmax = fmaxf(fmaxf(sv[0], sv[1]), fmaxf(sv[2], sv[3]));
        cmax = fmaxf(cmax, __shfl_xor(cmax, 1));
        cmax = fmaxf(cmax, __shfl_xor(cmax, 2));
        cmax = fmaxf(cmax, __shfl_xor(cmax, 4));
        cmax = fmaxf(cmax, __shfl_xor(cmax, 8));
        const bool rowok = (i <= 400);
        #pragma unroll
        for (int c = 0; c < 4; ++c)
            p[r][c] = rowok ? __expf(sv[c] - cmax) : 0.f;
        float cs = p[r][0] + p[r][1] + p[r][2] + p[r][3];
        cs += __shfl_xor(cs, 1);
        cs += __shfl_xor(cs, 2);
        cs += __shfl_xor(cs, 4);
        cs += __shfl_xor(cs, 8);
        if (tx == 0 && rowok) {
            long o = ((long)(h * 401 + i) * 7 + nb) * 2;
            Pml[o] = cmax;
            Pml[o + 1] = cs;
        }
    }
    #pragma unroll
    for (int c = 0; c < 4; ++c)
        *(float4*)&pT[tx * 4 + c][ty * 4] =
            make_float4(p[0][c], p[1][c], p[2][c], p[3][c]);
    __syncthreads();

    float o[4][4] = {};
    #pragma unroll 16
    for (int kk = 0; kk < 64; ++kk) {
        float4 a4 = *(const float4*)&pT[kk][ty * 4];
        float4 b4 = *(const float4*)&vs[kk][tx * 4];
        float av[4] = {a4.x, a4.y, a4.z, a4.w};
        float bv[4] = {b4.x, b4.y, b4.z, b4.w};
        #pragma unroll
        for (int r = 0; r < 4; ++r)
            #pragma unroll
            for (int c = 0; c < 4; ++c)
                o[r][c] = fmaf(av[r], bv[c], o[r][c]);
    }

    float* C = PO + (long)nb * PVS;
    #pragma unroll
    for (int r = 0; r < 4; ++r) {
        int m = m0 + ty * 4 + r;
        if (m > 400) continue;
        *(float4*)&C[(long)m * 512 + h * 64 + tx * 4] =
            make_float4(o[r][0], o[r][1], o[r][2], o[r][3]);
    }
    __syncthreads();
}

__device__ __forceinline__ void proj_body(
    float (*as)[68], float (*bs)[68], float (*wls)[8], int tid,
    int m0, int n0, int sk,
    const float* PO, const float* Pml, const float* projw, float* Pp)
{
    const int kBeg = sk * 64, kEnd = kBeg + 64;
    float acc[4][4] = {};

    if (tid < 64) {
        int row = m0 + tid;
        if (row <= 400) {
            const float* q = Pml + ((long)(sk * 401 + row) * 7) * 2;
            float M = -INFINITY;
            #pragma unroll
            for (int c = 0; c < 7; ++c) M = fmaxf(M, q[c * 2]);
            float D = 0.f;
            #pragma unroll
            for (int c = 0; c < 7; ++c) D += q[c * 2 + 1] * __expf(q[c * 2] - M);
            float iD = 1.f / D;
            #pragma unroll
            for (int c = 0; c < 7; ++c) wls[tid][c] = __expf(q[c * 2] - M) * iD;
        } else {
            #pragma unroll
            for (int c = 0; c < 7; ++c) wls[tid][c] = 0.f;
        }
    }
    __syncthreads();

    auto loadA = [&](int k0, float r4[4]) {
        r4[0] = r4[1] = r4[2] = r4[3] = 0.f;
        int lm = tid >> 2, gm = m0 + lm;
        if (gm > 400) return;
        int gk = k0 + (tid & 3) * 4;
        #pragma unroll
        for (int s = 0; s < 7; ++s) {
            float4 v = *(const float4*)(PO + (long)s * PVS + (long)gm * 512 + gk);
            float w = wls[lm][s];
            r4[0] = fmaf(w, v.x, r4[0]);
            r4[1] = fmaf(w, v.y, r4[1]);
            r4[2] = fmaf(w, v.z, r4[2]);
            r4[3] = fmaf(w, v.w, r4[3]);
        }
    };
    auto loadB = [&](int k0, float r[4]) {
        int gk = k0 + (tid >> 4);
        int gn = n0 + (tid & 15) * 4;
        float4 v = *(const float4*)(projw + (long)gk * 512 + gn);
        r[0]=v.x; r[1]=v.y; r[2]=v.z; r[3]=v.w;
    };
    gemm64<false>(kBeg, kEnd, tid, as, bs, acc, loadA, loadB);

    float* C = Pp + (long)sk * PVS;
    const int tx = tid & 15, ty = tid >> 4;
    #pragma unroll
    for (int r = 0; r < 4; ++r) {
        int m = m0 + ty * 4 + r;
        if (m > 400) continue;
        *(float4*)&C[(long)m * 512 + n0 + tx * 4] =
            make_float4(acc[r][0], acc[r][1], acc[r][2], acc[r][3]);
    }
    __syncthreads();
}

__device__ __forceinline__ void rowfuse_body(
    float* tiny, int tid, int r,
    const float* P, long slice, int skN, int rowOff,
    const float* bias, int doRelu,
    const float* resid, const float* cls,
    float* h0, const float* g, const float* b, float* xln)
{
    const int t = tid;
    float v0, v1;
    if (cls && r == 0) {
        v0 = cls[t]; v1 = cls[t + 256];
    } else {
        const float* p = P + (long)(r - rowOff) * DIM;
        v0 = bias[t]; v1 = bias[t + 256];
        for (int k = 0; k < skN; ++k) {
            v0 += p[(long)k * slice + t];
            v1 += p[(long)k * slice + t + 256];
        }
        if (resid) {
            v0 += resid[(long)r * DIM + t];
            v1 += resid[(long)r * DIM + t + 256];
        }
        if (doRelu) { v0 = fmaxf(v0, 0.f); v1 = fmaxf(v1, 0.f); }
    }
    h0[(long)r * DIM + t] = v0;
    h0[(long)r * DIM + t + 256] = v1;

    float s = v0 + v1, sq = v0 * v0 + v1 * v1;
    #pragma unroll
    for (int off = 32; off > 0; off >>= 1) {
        s += __shfl_down(s, off);
        sq += __shfl_down(sq, off);
    }
    float* ps = tiny, *pq = tiny + 4;
    int w = t >> 6, lane = t & 63;
    if (lane == 0) { ps[w] = s; pq[w] = sq; }
    __syncthreads();
    float Sm = ps[0] + ps[1] + ps[2] + ps[3];
    float Q = pq[0] + pq[1] + pq[2] + pq[3];
    float mean = Sm * (1.f / DIM);
    float var = Q * (1.f / DIM) - mean * mean;
    float inv = rsqrtf(var + LN_EPS);
    xln[(long)r * DIM + t]       = (v0 - mean) * inv * g[t] + b[t];
    xln[(long)r * DIM + t + 256] = (v1 - mean) * inv * g[t + 256] + b[t + 256];
    __syncthreads();
}

__device__ __forceinline__ void clsdec_body(
    float* sm, int tid, int h, int c,
    const float* xln, const float* qkvw, const float* Pkv,
    const float* qkvb, const int* pm, const float* pf, const float* Tt8,
    float* cms, float* cpv)
{
    const int kBeg = c * 64;
    float* q0 = sm;            // 64
    float* scraw = sm + 64;    // 64
    float* pp = sm + 128;      // 64
    float (*red)[64] = (float(*)[64])(sm + 192);   // 4x64
    float* rr = sm + 448;      // 2

    {
        int d = tid & 63, w4 = tid >> 6;
        const float* col = qkvw + h * 64 + d;
        float acc = 0.f;
        for (int k = w4 * 128; k < w4 * 128 + 128; ++k)
            acc = fmaf(xln[k], col[(long)k * 1536], acc);
        red[w4][d] = acc;
    }
    __syncthreads();
    if (tid < 64)
        q0[tid] = red[0][tid] + red[1][tid] + red[2][tid] + red[3][tid]
                  + qkvb[h * 64 + tid];
    __syncthreads();

    {
        int k = tid >> 2, q = tid & 3;
        int j = kBeg + k;
        float dot = 0.f;
        if (j < NP) {
            long base = (long)j * 1024 + h * 64 + q * 16;
            #pragma unroll
            for (int d = 0; d < 16; d += 4) {
                float4 x0 = *(const float4*)(Pkv + base + d);
                float4 x1 = *(const float4*)(Pkv + PKS + base + d);
                float4 x2 = *(const float4*)(Pkv + 2 * PKS + base + d);
                float4 x3 = *(const float4*)(Pkv + 3 * PKS + base + d);
                float4 bb = *(const float4*)(qkvb + 512 + h * 64 + q * 16 + d);
                float4 qq = *(const float4*)(q0 + q * 16 + d);
                dot = fmaf(qq.x, x0.x + x1.x + x2.x + x3.x + bb.x, dot);
                dot = fmaf(qq.y, x0.y + x1.y + x2.y + x3.y + bb.y, dot);
                dot = fmaf(qq.z, x0.z + x1.z + x2.z + x3.z + bb.z, dot);
                dot = fmaf(qq.w, x0.w + x1.w + x2.w + x3.w + bb.w, dot);
            }
        }
        dot += __shfl_down(dot, 2);
        dot += __shfl_down(dot, 1);
        if (q == 0) scraw[k] = dot;
    }
    __syncthreads();

    if (tid < 64) {
        int j = kBeg + tid;
        float s;
        if (j < NP) {
            int mm = pm[j];
            float fr = pf[j];
            float t0 = Tt8[(long)h * TSTRIDE + mm];
            float t1 = Tt8[(long)h * TSTRIDE + mm + 1];
            s = fmaf(scraw[tid], ATT_SCALE, fmaf(fr, t1 - t0, t0));
        } else {
            s = -INFINITY;
        }
        float m = s;
        #pragma unroll
        for (int off = 32; off > 0; off >>= 1)
            m = fmaxf(m, __shfl_xor(m, off));
        float e = (j < NP) ? __expf(s - m) : 0.f;
        float sum = e;
        #pragma unroll
        for (int off = 32; off > 0; off >>= 1)
            sum += __shfl_xor(sum, off);
        pp[tid] = e;
        if (tid == 0) { rr[0] = m; rr[1] = sum; }
    }
    __syncthreads();

    {
        int w = tid >> 6, d = tid & 63;
        float vb = qkvb[1024 + h * 64 + d];
        float acc = 0.f;
        for (int k = w; k < 64; k += 4) {
            int j = kBeg + k;
            if (j >= NP) break;
            long o = (long)j * 1024 + 512 + h * 64 + d;
            float v = Pkv[o] + Pkv[PKS + o] + Pkv[2 * PKS + o]
                      + Pkv[3 * PKS + o] + vb;
            acc = fmaf(pp[k], v, acc);
        }
        red[w][d] = acc;
    }
    __syncthreads();
    if (tid < 64) {
        cpv[((long)h * 7 + c) * 64 + tid] =
            red[0][tid] + red[1][tid] + red[2][tid] + red[3][tid];
        if (tid == 0) {
            cms[(h * 7 + c) * 2 + 0] = rr[0];
            cms[(h * 7 + c) * 2 + 1] = rr[1];
        }
    }
    __syncthreads();
}

__device__ __forceinline__ void clsproj_body(
    float* sm, int tid, int bk,
    const float* cms, const float* cpv,
    const float* projw, const float* projb, float* proj0)
{
    float* av = sm;                              // 512
    float (*red)[64] = (float(*)[64])(sm + 512); // 4x64
    for (int d = tid; d < 512; d += 256) {
        int h = d >> 6, dd = d & 63;
        float M = -INFINITY;
        #pragma unroll
        for (int c = 0; c < 7; ++c)
            M = fmaxf(M, cms[(h * 7 + c) * 2]);
        float Sx = 0.f, acc = 0.f;
        #pragma unroll
        for (int c = 0; c < 7; ++c) {
            float e = __expf(cms[(h * 7 + c) * 2] - M);
            Sx += cms[(h * 7 + c) * 2 + 1] * e;
            acc += cpv[((long)h * 7 + c) * 64 + dd] * e;
        }
        av[d] = acc / Sx;
    }
    __syncthreads();
    int gg = tid >> 6, n = bk * 64 + (tid & 63);
    float acc = 0.f;
    for (int k = gg * 128; k < gg * 128 + 128; ++k)
        acc = fmaf(av[k], projw[(long)k * 512 + n], acc);
    red[gg][tid & 63] = acc;
    __syncthreads();
    if (tid < 64)
        proj0[bk * 64 + tid] = red[0][tid] + red[1][tid] + red[2][tid]
                               + red[3][tid] + projb[bk * 64 + tid];
    __syncthreads();
}

__device__ __forceinline__ void final_body(
    float* tiny, int tid,
    const float* h0, const float* proj0,
    const float* g, const float* b,
    const float* fc2w, const float* fc2b, float* out)
{
    const int t = tid;
    float v0 = h0[t] + proj0[t];
    float v1 = h0[t + 256] + proj0[t + 256];
    float s = v0 + v1, sq = v0 * v0 + v1 * v1;
    #pragma unroll
    for (int off = 32; off > 0; off >>= 1) {
        s += __shfl_down(s, off);
        sq += __shfl_down(sq, off);
    }
    float *ps = tiny, *pq = tiny + 4, *pc0 = tiny + 8, *pc1 = tiny + 12;
    int w = t >> 6, lane = t & 63;
    if (lane == 0) { ps[w] = s; pq[w] = sq; }
    __syncthreads();
    float Sm = ps[0] + ps[1] + ps[2] + ps[3];
    float Q = pq[0] + pq[1] + pq[2] + pq[3];
    float mean = Sm * (1.f / DIM);
    float var = Q * (1.f / DIM) - mean * mean;
    float inv = rsqrtf(var + LN_EPS);
    float n0 = (v0 - mean) * inv * g[t] + b[t];
    float n1 = (v1 - mean) * inv * g[t + 256] + b[t + 256];
    float c0 = n0 * fc2w[t * 2]     + n1 * fc2w[(t + 256) * 2];
    float c1 = n0 * fc2w[t * 2 + 1] + n1 * fc2w[(t + 256) * 2 + 1];
    #pragma unroll
    for (int off = 32; off > 0; off >>= 1) {
        c0 += __shfl_down(c0, off);
        c1 += __shfl_down(c1, off);
    }
    if (lane == 0) { pc0[w] = c0; pc1[w] = c1; }
    __syncthreads();
    if (t == 0) {
        out[0] = pc0[0] + pc0[1] + pc0[2] + pc0[3] + fc2b[0];
        out[1] = pc1[0] + pc1[1] + pc1[2] + pc1[3] + fc2b[1];
    }
}

// ---------------------------------------------------------------------------
// Parameter block
// ---------------------------------------------------------------------------
struct KP {
    const float *hin, *coords, *fc1w, *fc1b, *clstok;
    const float *l1g, *l1b, *w1_0, *b1_0, *w2_0, *b2_0;
    const float *l1qkvw, *l1qkvb, *l1projw, *l1projb;
    const float *l2g, *l2b, *w1_1, *b1_1, *w2_1, *b2_1;
    const float *l2qkvw, *l2qkvb, *l2projw, *l2projb;
    const float *ng, *nb, *fc2w, *fc2b;
    float *out;
    float *h0, *xln, *PO, *T;
    int *pm; float *pf;
    float *Pq, *qkv, *Pp, *proj0, *cms, *cpv, *Pml;
    unsigned *gen; unsigned *flags;
};

// ---------------------------------------------------------------------------
// The whole network as one persistent kernel with 10 grid barriers.
// LDS: 8704 floats (34.8KB): as[0..1088) bs[1088..2176) wls[2176..2688)
//      flash pT aliases [0..4352), vs at [4352..8704).
// ---------------------------------------------------------------------------
__global__ __launch_bounds__(256, 3) void fused_kernel(KP P)
{
    __shared__ float smem[8704];   // 34.8 KB
    __shared__ float tiny[16];
    float (*as)[68] = (float(*)[68])smem;
    float (*bs)[68] = (float(*)[68])(smem + 1088);
    float (*pT)[68] = (float(*)[68])smem;            // post-gemm64 alias
    float (*vs)[68] = (float(*)[68])(smem + 4352);
    float (*wls)[8] = (float(*)[8])(smem + 2176);
    const int tid = threadIdx.x, bid = blockIdx.x;
    unsigned bt = 0;

    // ---- phase 0: fc1 split-K16 + CPB angle tables + pair->angle map ----
    for (int vb = bid; vb < 1655; vb += GRID) {
        if (vb < 896) {
            int sk = vb / 56, rem = vb % 56;
            int m0 = (rem % 7) * 64, n0 = (rem / 7) * 64;
            int kBeg = sk * 64, kEnd = kBeg + 64;
            float acc[4][4] = {};
            auto loadA = [&](int k0, float r[4]) {
                r[0]=r[1]=r[2]=r[3]=0.f;
                int gm = m0 + (tid >> 2);
                if (gm >= 400) return;
                int gk = k0 + (tid & 3) * 4;
                float4 v = *(const float4*)(P.hin + (long)gm * 1024 + gk);
                r[0]=v.x; r[1]=v.y; r[2]=v.z; r[3]=v.w;
            };
            auto loadB = [&](int k0, float r[4]) {
                int gk = k0 + (tid >> 4);
                int gn = n0 + (tid & 15) * 4;
                float4 v = *(const float4*)(P.fc1w + (long)gk * 512 + gn);
                r[0]=v.x; r[1]=v.y; r[2]=v.z; r[3]=v.w;
            };
            gemm64<false>(kBeg, kEnd, tid, as, bs, acc, loadA, loadB);
            float* C = P.Pp + (long)sk * PVS;
            const int tx = tid & 15, ty = tid >> 4;
            #pragma unroll
            for (int r = 0; r < 4; ++r) {
                int m = m0 + ty * 4 + r;
                if (m >= 400) continue;
                *(float4*)&C[(long)m * 512 + n0 + tx * 4] =
                    make_float4(acc[r][0], acc[r][1], acc[r][2], acc[r][3]);
            }
        } else if (vb < 1026) {
            int tb = vb - 896;
            int z = tb / 65, ab = tb % 65;
            const float* w1 = z ? P.w1_1 : P.w1_0;
            const float* b1 = z ? P.b1_1 : P.b1_0;
            const float* w2 = z ? P.w2_1 : P.w2_0;
            const float* b2 = z ? P.b2_1 : P.b2_0;
            float (*red)[64][8] = (float(*)[64][8])smem;
            const int lane = tid & 63, wv = tid >> 6;
            float ca = 0.f, sa = 0.f;
            if (ab != 64) {
                float th = fmaf((float)(ab * 64 + lane),
                                (float)(2.0 * M_PI / CPB_M), -(float)M_PI);
                sincosf(th, &sa, &ca);
            } else if (lane == 0) {
                sincosf((float)M_PI, &sa, &ca);
            }
            float a8[8] = {};
            const int kbeg = wv * 128;
            #pragma unroll 4
            for (int k = kbeg; k < kbeg + 128; ++k) {
                float hk = fmaxf(fmaf(ca, w1[k],
                                      fmaf(sa, w1[512 + k], b1[k])), 0.f);
                #pragma unroll
                for (int h2 = 0; h2 < 8; ++h2)
                    a8[h2] = fmaf(hk, w2[k * 8 + h2], a8[h2]);
            }
            #pragma unroll
            for (int h2 = 0; h2 < 8; ++h2) red[wv][lane][h2] = a8[h2];
            __syncthreads();
            if (tid < 64) {
                int aidx = ab * 64 + tid;
                if (aidx <= CPB_M + 1) {
                    #pragma unroll
                    for (int h2 = 0; h2 < 8; ++h2)
                        P.T[(long)(z * 8 + h2) * TSTRIDE + aidx] =
                            red[0][tid][h2] + red[1][tid][h2] +
                            red[2][tid][h2] + red[3][tid][h2] + b2[h2];
                }
            }
        } else {
            int p = (vb - 1026) * 256 + tid;
            if (p < NP * NP) {
                int i = p / NP, j = p - i * NP;
                float xi = (i == 0) ? 0.f : P.coords[(i - 1) * 2];
                float yi = (i == 0) ? 0.f : P.coords[(i - 1) * 2 + 1];
                float xj = (j == 0) ? 0.f : P.coords[(j - 1) * 2];
                float yj = (j == 0) ? 0.f : P.coords[(j - 1) * 2 + 1];
                float rx = xi - xj, ry = yi - yj;
                int mm; float fr;
                if (rx == 0.f && ry == 0.f) {
                    mm = CPB_M + 1; fr = 0.f;
                } else {
                    float x = (atan2f(ry, rx) + 3.14159265358979f)
                              * (float)(CPB_M / (2.0 * M_PI));
                    int mi = (int)x;
                    fr = x - (float)mi;
                    mm = (mi >= CPB_M) ? mi - CPB_M : mi;
                }
                P.pm[i * 416 + j] = mm;
                P.pf[i * 416 + j] = fr;
            }
        }
        __syncthreads();
    }
    gsync(P.gen, P.flags, ++bt);

    // ---- phase 1: fc1 reduce + relu + cls + LN(l1) -> h0, xln ----
    for (int vb = bid; vb < 401; vb += GRID)
        rowfuse_body(tiny, tid, vb, P.Pp, PVS, 16, 1, P.fc1b, 1,
                     nullptr, P.clstok, P.h0, P.l1g, P.l1b, P.xln);
    gsync(P.gen, P.flags, ++bt);

    // ---- phase 2: layer-1 qkv GEMM split-K4 (7x24x4 = 672 tiles) ----
    for (int vb = bid; vb < 672; vb += GRID) {
        int x = vb % 7, y = (vb / 7) % 24, sk = vb / 168;
        gemm_split_body(as, bs, tid, x * 64, y * 64, sk,
                        P.xln, 512, P.l1qkvw, 1536,
                        P.Pq, 1536, PQS, 401, 512, 4);
    }
    gsync(P.gen, P.flags, ++bt);

    // ---- phase 3: qkv reduce + bias (602 tiles) ----
    for (int vb = bid; vb < 602; vb += GRID)
        reduce_body(vb, tid, P.Pq, PQS, 4, P.l1qkvb, P.qkv, 401 * 1536, 1536);
    gsync(P.gen, P.flags, ++bt);

    // ---- phase 4: fused flash attention tiles (7x7x8 = 392) ----
    for (int vb = bid; vb < 392; vb += GRID) {
        int x = vb % 7, nb = (vb / 7) % 7, h = vb / 49;
        flash_body(as, bs, pT, vs, tid, x * 64, nb, h,
                   P.qkv, P.pm, P.pf, P.T, P.PO, P.Pml);
    }
    gsync(P.gen, P.flags, ++bt);

    // ---- phase 5: proj with LSE combine (7x8x8 = 448) ----
    for (int vb = bid; vb < 448; vb += GRID) {
        int x = vb % 7, y = (vb / 7) % 8, sk = vb / 56;
        proj_body(as, bs, wls, tid, x * 64, y * 64, sk,
                  P.PO, P.Pml, P.l1projw, P.Pp);
    }
    gsync(P.gen, P.flags, ++bt);

    // ---- phase 6: proj reduce + resid + LN(l2) -> h0, xln ----
    for (int vb = bid; vb < 401; vb += GRID)
        rowfuse_body(tiny, tid, vb, P.Pp, PVS, 8, 0, P.l1projb, 0,
                     P.h0, nullptr, P.h0, P.l2g, P.l2b, P.xln);
    gsync(P.gen, P.flags, ++bt);

    // ---- phase 7: layer-2 K,V GEMM split-K4 (7x16x4 = 448) ----
    for (int vb = bid; vb < 448; vb += GRID) {
        int x = vb % 7, y = (vb / 7) % 16, sk = vb / 112;
        gemm_split_body(as, bs, tid, x * 64, y * 64, sk,
                        P.xln, 512, P.l2qkvw + 512, 1536,
                        P.Pq, 1024, PKS, 401, 512, 4);
    }
    gsync(P.gen, P.flags, ++bt);

    // ---- phase 8: CLS flash-decode (8x7 = 56) ----
    for (int vb = bid; vb < 56; vb += GRID)
        clsdec_body(smem, tid, vb % 8, vb / 8,
                    P.xln, P.l2qkvw, P.Pq, P.l2qkvb,
                    P.pm, P.pf, P.T + 8L * TSTRIDE, P.cms, P.cpv);
    gsync(P.gen, P.flags, ++bt);

    // ---- phase 9: CLS proj partials (8 n-chunks) ----
    for (int vb = bid; vb < 8; vb += GRID)
        clsproj_body(smem, tid, vb, P.cms, P.cpv,
                     P.l2projw, P.l2projb, P.proj0);
    gsync(P.gen, P.flags, ++bt);

    // ---- phase 10: residual + LN + fc2 -> out (1 block) ----
    if (bid == 0)
        final_body(tiny, tid, P.h0, P.proj0, P.ng, P.nb,
                   P.fc2w, P.fc2b, P.out);
}

// ---------------------------------------------------------------------------
extern "C" void kernel_launch(void* const* d_in, const int* in_sizes, int n_in,
                              void* d_out, int out_size, void* d_ws, size_t ws_size,
                              hipStream_t stream)
{
    float* ws = (float*)d_ws;
    float* h0   = ws;                    ws += 401L * 512;
    float* xln  = ws;                    ws += 401L * 512;
    float* PO   = ws;                    ws += 7L * PVS;
    float* T    = ws;                    ws += 16L * TSTRIDE;
    int*   pm   = (int*)ws;              ws += 401L * 416;
    float* pf   = ws;                    ws += 401L * 416;
    float* Pq   = ws;                    ws += 4L * PQS;   // also layer-2 kv
    float* qkv  = ws;                    ws += 401L * 1536;
    float* Pp   = ws;                    ws += 16L * PVS;
    float* proj0 = ws;                   ws += 512;
    float* cms  = ws;                    ws += 8L * 7 * 2;
    float* cpv  = ws;                    ws += 8L * 7 * 64;
    float* Pml  = ws;                    ws += 8L * 401 * 7 * 2;
    unsigned* gen   = (unsigned*)ws;     ws += 32;             // 128B line
    unsigned* flags = (unsigned*)ws;     ws += GRID * FSTRIDE; // 96KB

    hipMemsetAsync(gen, 0, (32 + GRID * FSTRIDE) * 4, stream);

    KP P;
    P.hin    = (const float*)d_in[0];
    P.coords = (const float*)d_in[1];
    P.fc1w   = (const float*)d_in[2];
    P.fc1b   = (const float*)d_in[3];
    P.clstok = (const float*)d_in[4];
    P.l1g = (const float*)d_in[5];  P.l1b = (const float*)d_in[6];
    P.w1_0 = (const float*)d_in[7]; P.b1_0 = (const float*)d_in[8];
    P.w2_0 = (const float*)d_in[9]; P.b2_0 = (const float*)d_in[10];
    P.l1qkvw = (const float*)d_in[11]; P.l1qkvb = (const float*)d_in[12];
    P.l1projw = (const float*)d_in[13]; P.l1projb = (const float*)d_in[14];
    P.l2g = (const float*)d_in[15]; P.l2b = (const float*)d_in[16];
    P.w1_1 = (const float*)d_in[17]; P.b1_1 = (const float*)d_in[18];
    P.w2_1 = (const float*)d_in[19]; P.b2_1 = (const float*)d_in[20];
    P.l2qkvw = (const float*)d_in[21]; P.l2qkvb = (const float*)d_in[22];
    P.l2projw = (const float*)d_in[23]; P.l2projb = (const float*)d_in[24];
    P.ng = (const float*)d_in[25]; P.nb = (const float*)d_in[26];
    P.fc2w = (const float*)d_in[27]; P.fc2b = (const float*)d_in[28];
    P.out = (float*)d_out;
    P.h0 = h0; P.xln = xln; P.PO = PO; P.T = T;
    P.pm = pm; P.pf = pf;
    P.Pq = Pq; P.qkv = qkv; P.Pp = Pp; P.proj0 = proj0;
    P.cms = cms; P.cpv = cpv; P.Pml = Pml;
    P.gen = gen; P.flags = flags;

    fused_kernel<<<GRID, 256, 0, stream>>>(P);
}

// Round 5
// 242.682 us; speedup vs baseline: 9.5434x; 9.5434x over previous
//
#include <hip/hip_runtime.h>
#include <math.h>

#define NP 401            // tokens incl. CLS (400 patches, side=20, add=0)
#define DIM 512
#define LN_EPS 1e-5f
#define ATT_SCALE 0.125f
#define CPB_M 4096        // angle-table resolution (interp err ~2e-5 << tol)
#define TSTRIDE (CPB_M + 64)
#define PVS (401L * 512)  // fc1 / pv / proj partial slice stride

// ---------------------------------------------------------------------------
// 64x64-tile GEMM body: 256 thr, 4x4 micro-tile, K-chunk 16, register
// double-buffered staging via caller-supplied loaders.
// ---------------------------------------------------------------------------
template<bool TB, typename LA, typename LB>
__device__ __forceinline__ void gemm64(
    int kBeg, int kEnd, int tid,
    float (*as)[68], float (*bs)[68], float (&acc)[4][4],
    LA&& loadA, LB&& loadB)
{
    float aR[4], bR[4];
    loadA(kBeg, aR);
    loadB(kBeg, bR);
    for (int k0 = kBeg; k0 < kEnd; k0 += 16) {
        const int arow = tid >> 2, aq = tid & 3;
        as[aq * 4 + 0][arow] = aR[0];
        as[aq * 4 + 1][arow] = aR[1];
        as[aq * 4 + 2][arow] = aR[2];
        as[aq * 4 + 3][arow] = aR[3];
        if (!TB) {
            *(float4*)&bs[tid >> 4][(tid & 15) * 4] =
                make_float4(bR[0], bR[1], bR[2], bR[3]);
        } else {
            bs[aq * 4 + 0][arow] = bR[0];
            bs[aq * 4 + 1][arow] = bR[1];
            bs[aq * 4 + 2][arow] = bR[2];
            bs[aq * 4 + 3][arow] = bR[3];
        }
        __syncthreads();
        float nA[4] = {0.f,0.f,0.f,0.f}, nB[4] = {0.f,0.f,0.f,0.f};
        if (k0 + 16 < kEnd) { loadA(k0 + 16, nA); loadB(k0 + 16, nB); }
        const int tx = tid & 15, ty = tid >> 4;
        #pragma unroll
        for (int kk = 0; kk < 16; ++kk) {
            float4 a4 = *(const float4*)&as[kk][ty * 4];
            float4 b4 = *(const float4*)&bs[kk][tx * 4];
            float av[4] = {a4.x, a4.y, a4.z, a4.w};
            float bv[4] = {b4.x, b4.y, b4.z, b4.w};
            #pragma unroll
            for (int r = 0; r < 4; ++r)
                #pragma unroll
                for (int c = 0; c < 4; ++c)
                    acc[r][c] = fmaf(av[r], bv[c], acc[r][c]);
        }
        __syncthreads();
        #pragma unroll
        for (int j = 0; j < 4; ++j) { aR[j] = nA[j]; bR[j] = nB[j]; }
    }
}

// ---------------------------------------------------------------------------
// Dense-K GEMM with fused bias: C[m][n] = A[m,:]·B[:,n] + bias[n].
// A is (401 x 512) lda=512. grid (7, N/64). No split-K, no reduce pass.
// ---------------------------------------------------------------------------
__global__ __launch_bounds__(256) void gemm_bias_kernel(
    const float* __restrict__ A,
    const float* __restrict__ B, int ldb,
    const float* __restrict__ bias,
    float* __restrict__ C, int ldc)
{
    __shared__ float as[16][68], bs[16][68];
    const int tid = threadIdx.x;
    const int m0 = blockIdx.x * 64, n0 = blockIdx.y * 64;
    float acc[4][4] = {};

    auto loadA = [&](int k0, float r[4]) {
        int gm = m0 + (tid >> 2);
        if (gm > 400) { r[0]=r[1]=r[2]=r[3]=0.f; return; }
        int gk = k0 + (tid & 3) * 4;
        float4 v = *(const float4*)(A + (long)gm * 512 + gk);
        r[0]=v.x; r[1]=v.y; r[2]=v.z; r[3]=v.w;
    };
    auto loadB = [&](int k0, float r[4]) {
        int gk = k0 + (tid >> 4);
        int gn = n0 + (tid & 15) * 4;
        float4 v = *(const float4*)(B + (long)gk * ldb + gn);
        r[0]=v.x; r[1]=v.y; r[2]=v.z; r[3]=v.w;
    };
    gemm64<false>(0, 512, tid, as, bs, acc, loadA, loadB);

    const int tx = tid & 15, ty = tid >> 4;
    const float4 bv = *(const float4*)(bias + n0 + tx * 4);
    #pragma unroll
    for (int r = 0; r < 4; ++r) {
        int m = m0 + ty * 4 + r;
        if (m > 400) continue;
        *(float4*)&C[(long)m * ldc + n0 + tx * 4] =
            make_float4(acc[r][0] + bv.x, acc[r][1] + bv.y,
                        acc[r][2] + bv.z, acc[r][3] + bv.w);
    }
}

// ---------------------------------------------------------------------------
// Fused flash attention tile (layer 1): one block = one (m-tile, kv-tile,
// head). QK^T via gemm64, CPB bias interp, tile-local softmax, P·V through
// LDS. Writes un-normalized O-partial per kv-chunk + (max,sum) per row-chunk.
// grid (7, 7, 8).
// ---------------------------------------------------------------------------
__global__ __launch_bounds__(256) void flash_kernel(
    const float* __restrict__ qkv,
    const int* __restrict__ pm, const float* __restrict__ pf,
    const float* __restrict__ T,
    float* __restrict__ PO,        // (7, 401, 512) chunk partials
    float* __restrict__ Pml)       // (8, 401, 7, 2)
{
    __shared__ float as[16][68], bs[16][68];
    __shared__ float pT[64][68];   // P transposed: [key][row]
    __shared__ float vs[64][68];   // V tile: [key][dim]
    const int tid = threadIdx.x;
    const int m0 = blockIdx.x * 64, nb = blockIdx.y, h = blockIdx.z;
    const int n0 = nb * 64;
    float acc[4][4] = {};

    // V tile -> registers early (global loads overlap the QK gemm)
    float vreg[4][4];
    {
        int key = n0 + (tid >> 2);
        int d0 = (tid & 3) * 16;
        if (key <= 400) {
            const float* p = qkv + (long)key * 1536 + 1024 + h * 64 + d0;
            #pragma unroll
            for (int i = 0; i < 4; ++i) {
                float4 v = *(const float4*)(p + i * 4);
                vreg[i][0] = v.x; vreg[i][1] = v.y;
                vreg[i][2] = v.z; vreg[i][3] = v.w;
            }
        } else {
            #pragma unroll
            for (int i = 0; i < 4; ++i)
                vreg[i][0] = vreg[i][1] = vreg[i][2] = vreg[i][3] = 0.f;
        }
    }

    auto loadQ = [&](int k0, float r[4]) {
        int gm = m0 + (tid >> 2);
        if (gm > 400) { r[0]=r[1]=r[2]=r[3]=0.f; return; }
        int gk = k0 + (tid & 3) * 4;
        float4 v = *(const float4*)(qkv + (long)gm * 1536 + h * 64 + gk);
        r[0]=v.x; r[1]=v.y; r[2]=v.z; r[3]=v.w;
    };
    auto loadK = [&](int k0, float r[4]) {
        int gn = n0 + (tid >> 2);
        if (gn > 400) { r[0]=r[1]=r[2]=r[3]=0.f; return; }
        int gk = k0 + (tid & 3) * 4;
        float4 v = *(const float4*)(qkv + (long)gn * 1536 + 512 + h * 64 + gk);
        r[0]=v.x; r[1]=v.y; r[2]=v.z; r[3]=v.w;
    };
    gemm64<true>(0, 64, tid, as, bs, acc, loadQ, loadK);
    // gemm64 exits right after a __syncthreads(): safe to write pT/vs now.

    // V regs -> LDS
    {
        int key = tid >> 2, d0 = (tid & 3) * 16;
        #pragma unroll
        for (int i = 0; i < 4; ++i)
            *(float4*)&vs[key][d0 + i * 4] =
                make_float4(vreg[i][0], vreg[i][1], vreg[i][2], vreg[i][3]);
    }

    // CPB bias + tile-local softmax; keep p in regs for transposed store
    const int tx = tid & 15, ty = tid >> 4;
    const float* Tt = T + (long)h * TSTRIDE;
    float p[4][4];
    #pragma unroll
    for (int r = 0; r < 4; ++r) {
        int i = m0 + ty * 4 + r;
        float sv[4];
        #pragma unroll
        for (int c = 0; c < 4; ++c) {
            int j = n0 + tx * 4 + c;
            if (i <= 400 && j <= 400) {
                int id = i * 416 + j;
                int mm = pm[id];
                float fr = pf[id];
                float t0 = Tt[mm], t1 = Tt[mm + 1];
                sv[c] = fmaf(acc[r][c], ATT_SCALE, fmaf(fr, t1 - t0, t0));
            } else {
                sv[c] = -INFINITY;
            }
        }
        float cmax = fmaxf(fmaxf(sv[0], sv[1]), fmaxf(sv[2], sv[3]));
        cmax = fmaxf(cmax, __shfl_xor(cmax, 1));
        cmax = fmaxf(cmax, __shfl_xor(cmax, 2));
        cmax = fmaxf(cmax, __shfl_xor(cmax, 4));
        cmax = fmaxf(cmax, __shfl_xor(cmax, 8));
        const bool rowok = (i <= 400);
        #pragma unroll
        for (int c = 0; c < 4; ++c)
            p[r][c] = rowok ? __expf(sv[c] - cmax) : 0.f;
        float cs = p[r][0] + p[r][1] + p[r][2] + p[r][3];
        cs += __shfl_xor(cs, 1);
        cs += __shfl_xor(cs, 2);
        cs += __shfl_xor(cs, 4);
        cs += __shfl_xor(cs, 8);
        if (tx == 0 && rowok) {
            long o = ((long)(h * 401 + i) * 7 + nb) * 2;
            Pml[o] = cmax;
            Pml[o + 1] = cs;
        }
    }
    // transposed store: pT[key][row], float4 over rows (contiguous)
    #pragma unroll
    for (int c = 0; c < 4; ++c)
        *(float4*)&pT[tx * 4 + c][ty * 4] =
            make_float4(p[0][c], p[1][c], p[2][c], p[3][c]);
    __syncthreads();

    // P·V: o[r][c] += sum_k pT[k][row] * vs[k][dim]; LDS-only operands
    float o[4][4] = {};
    #pragma unroll 16
    for (int kk = 0; kk < 64; ++kk) {
        float4 a4 = *(const float4*)&pT[kk][ty * 4];
        float4 b4 = *(const float4*)&vs[kk][tx * 4];
        float av[4] = {a4.x, a4.y, a4.z, a4.w};
        float bv[4] = {b4.x, b4.y, b4.z, b4.w};
        #pragma unroll
        for (int r = 0; r < 4; ++r)
            #pragma unroll
            for (int c = 0; c < 4; ++c)
                o[r][c] = fmaf(av[r], bv[c], o[r][c]);
    }

    float* C = PO + (long)nb * PVS;
    #pragma unroll
    for (int r = 0; r < 4; ++r) {
        int m = m0 + ty * 4 + r;
        if (m > 400) continue;
        *(float4*)&C[(long)m * 512 + h * 64 + tx * 4] =
            make_float4(o[r][0], o[r][1], o[r][2], o[r][3]);
    }
}

// ---------------------------------------------------------------------------
// proj (layer 1), split-K8 (one head per z), LSE combine of the 7 flash
// O-partials folded into the A-loader. grid (7,8,8).
// ---------------------------------------------------------------------------
__global__ __launch_bounds__(256) void proj_kernel(
    const float* __restrict__ PO, const float* __restrict__ Pml,
    const float* __restrict__ projw, float* __restrict__ Pp)
{
    __shared__ float as[16][68], bs[16][68];
    __shared__ float wls[64][8];
    const int tid = threadIdx.x;
    const int m0 = blockIdx.x * 64, n0 = blockIdx.y * 64, sk = blockIdx.z;
    const int kBeg = sk * 64, kEnd = kBeg + 64;
    float acc[4][4] = {};

    // per-row LSE merge weights for head sk
    if (tid < 64) {
        int row = m0 + tid;
        if (row <= 400) {
            const float* q = Pml + ((long)(sk * 401 + row) * 7) * 2;
            float M = -INFINITY;
            #pragma unroll
            for (int c = 0; c < 7; ++c) M = fmaxf(M, q[c * 2]);
            float D = 0.f;
            #pragma unroll
            for (int c = 0; c < 7; ++c) D += q[c * 2 + 1] * __expf(q[c * 2] - M);
            float iD = 1.f / D;
            #pragma unroll
            for (int c = 0; c < 7; ++c) wls[tid][c] = __expf(q[c * 2] - M) * iD;
        } else {
            #pragma unroll
            for (int c = 0; c < 7; ++c) wls[tid][c] = 0.f;
        }
    }
    __syncthreads();

    auto loadA = [&](int k0, float r4[4]) {
        r4[0] = r4[1] = r4[2] = r4[3] = 0.f;
        int lm = tid >> 2, gm = m0 + lm;
        if (gm > 400) return;
        int gk = k0 + (tid & 3) * 4;
        #pragma unroll
        for (int s = 0; s < 7; ++s) {
            float4 v = *(const float4*)(PO + (long)s * PVS + (long)gm * 512 + gk);
            float w = wls[lm][s];
            r4[0] = fmaf(w, v.x, r4[0]);
            r4[1] = fmaf(w, v.y, r4[1]);
            r4[2] = fmaf(w, v.z, r4[2]);
            r4[3] = fmaf(w, v.w, r4[3]);
        }
    };
    auto loadB = [&](int k0, float r[4]) {
        int gk = k0 + (tid >> 4);
        int gn = n0 + (tid & 15) * 4;
        float4 v = *(const float4*)(projw + (long)gk * 512 + gn);
        r[0]=v.x; r[1]=v.y; r[2]=v.z; r[3]=v.w;
    };
    gemm64<false>(kBeg, kEnd, tid, as, bs, acc, loadA, loadB);

    float* C = Pp + (long)sk * PVS;
    const int tx = tid & 15, ty = tid >> 4;
    #pragma unroll
    for (int r = 0; r < 4; ++r) {
        int m = m0 + ty * 4 + r;
        if (m > 400) continue;
        *(float4*)&C[(long)m * 512 + n0 + tx * 4] =
            make_float4(acc[r][0], acc[r][1], acc[r][2], acc[r][3]);
    }
}

// ---------------------------------------------------------------------------
// Per-row split-K reduce + epilogue + LayerNorm. grid 401.
// ---------------------------------------------------------------------------
__global__ __launch_bounds__(256) void rowfuse_kernel(
    const float* __restrict__ P, long slice, int skN, int rowOff,
    const float* __restrict__ bias, int doRelu,
    const float* __restrict__ resid, const float* __restrict__ cls,
    float* __restrict__ h0,
    const float* __restrict__ g, const float* __restrict__ b,
    float* __restrict__ xln)
{
    const int r = blockIdx.x, t = threadIdx.x;
    float v0, v1;
    if (cls && r == 0) {
        v0 = cls[t]; v1 = cls[t + 256];
    } else {
        const float* p = P + (long)(r - rowOff) * DIM;
        v0 = bias[t]; v1 = bias[t + 256];
        for (int k = 0; k < skN; ++k) {
            v0 += p[(long)k * slice + t];
            v1 += p[(long)k * slice + t + 256];
        }
        if (resid) {
            v0 += resid[(long)r * DIM + t];
            v1 += resid[(long)r * DIM + t + 256];
        }
        if (doRelu) { v0 = fmaxf(v0, 0.f); v1 = fmaxf(v1, 0.f); }
    }
    h0[(long)r * DIM + t] = v0;
    h0[(long)r * DIM + t + 256] = v1;

    float s = v0 + v1, sq = v0 * v0 + v1 * v1;
    #pragma unroll
    for (int off = 32; off > 0; off >>= 1) {
        s += __shfl_down(s, off);
        sq += __shfl_down(sq, off);
    }
    __shared__ float ps[4], pq[4];
    int w = t >> 6, lane = t & 63;
    if (lane == 0) { ps[w] = s; pq[w] = sq; }
    __syncthreads();
    float Sm = ps[0] + ps[1] + ps[2] + ps[3];
    float Q = pq[0] + pq[1] + pq[2] + pq[3];
    float mean = Sm * (1.f / DIM);
    float var = Q * (1.f / DIM) - mean * mean;
    float inv = rsqrtf(var + LN_EPS);
    xln[(long)r * DIM + t]       = (v0 - mean) * inv * g[t] + b[t];
    xln[(long)r * DIM + t + 256] = (v1 - mean) * inv * g[t + 256] + b[t + 256];
}

// ---------------------------------------------------------------------------
// CLS flash-decode (layer 2): grid (8 heads, 7 key-chunks of 64).
// q0 inline from xln row 0; K/V DENSE (bias already folded by gemm_bias).
// Also zeroes the cls_proj completion counter (block (0,0)).
// ---------------------------------------------------------------------------
__global__ __launch_bounds__(256) void cls_decode_kernel(
    const float* __restrict__ xln, const float* __restrict__ qkvw,
    const float* __restrict__ kv, const float* __restrict__ qkvb,
    const int* __restrict__ pm, const float* __restrict__ pf,
    const float* __restrict__ T,
    float* __restrict__ cms, float* __restrict__ cpv,
    unsigned* __restrict__ cnt)
{
    const int h = blockIdx.x, c = blockIdx.y, tid = threadIdx.x;
    const int kBeg = c * 64;
    __shared__ float q0[64], scraw[64], p[64], red[4][64], rr[2];

    if (h == 0 && c == 0 && tid == 0) *cnt = 0u;   // init for cls_proj

    // q0[d] = sum_k xln[0][k] * Wq[k][h*64+d] + bq[h*64+d]; 4-wave k-split
    {
        int d = tid & 63, w4 = tid >> 6;
        const float* col = qkvw + h * 64 + d;
        float acc = 0.f;
        for (int k = w4 * 128; k < w4 * 128 + 128; ++k)
            acc = fmaf(xln[k], col[(long)k * 1536], acc);
        red[w4][d] = acc;
    }
    __syncthreads();
    if (tid < 64)
        q0[tid] = red[0][tid] + red[1][tid] + red[2][tid] + red[3][tid]
                  + qkvb[h * 64 + tid];
    __syncthreads();

    // scores: key k = tid>>2 (4 lanes/key, 16 dims each), shuffle-reduce
    {
        int k = tid >> 2, q = tid & 3;
        int j = kBeg + k;
        float dot = 0.f;
        if (j < NP) {
            long base = (long)j * 1024 + h * 64 + q * 16;   // K cols 0..512
            #pragma unroll
            for (int d = 0; d < 16; d += 4) {
                float4 x0 = *(const float4*)(kv + base + d);
                float4 qq = *(const float4*)(q0 + q * 16 + d);
                dot = fmaf(qq.x, x0.x, dot);
                dot = fmaf(qq.y, x0.y, dot);
                dot = fmaf(qq.z, x0.z, dot);
                dot = fmaf(qq.w, x0.w, dot);
            }
        }
        dot += __shfl_down(dot, 2);
        dot += __shfl_down(dot, 1);
        if (q == 0) scraw[k] = dot;
    }
    __syncthreads();

    // bias + local softmax on wave 0
    if (tid < 64) {
        int j = kBeg + tid;
        float s;
        if (j < NP) {
            int mm = pm[j];                   // row 0 of pair map
            float fr = pf[j];
            const float* Tt = T + (long)h * TSTRIDE;
            float t0 = Tt[mm], t1 = Tt[mm + 1];
            s = fmaf(scraw[tid], ATT_SCALE, fmaf(fr, t1 - t0, t0));
        } else {
            s = -INFINITY;
        }
        float m = s;
        #pragma unroll
        for (int off = 32; off > 0; off >>= 1)
            m = fmaxf(m, __shfl_xor(m, off));
        float e = (j < NP) ? __expf(s - m) : 0.f;
        float sum = e;
        #pragma unroll
        for (int off = 32; off > 0; off >>= 1)
            sum += __shfl_xor(sum, off);
        p[tid] = e;
        if (tid == 0) { rr[0] = m; rr[1] = sum; }
    }
    __syncthreads();

    // partial PV: d = lane, wave w handles keys k ≡ w (mod 4)
    {
        int w = tid >> 6, d = tid & 63;
        float acc = 0.f;
        for (int k = w; k < 64; k += 4) {
            int j = kBeg + k;
            if (j >= NP) break;
            long o = (long)j * 1024 + 512 + h * 64 + d;     // V cols 512..1024
            acc = fmaf(p[k], kv[o], acc);
        }
        red[w][d] = acc;
    }
    __syncthreads();
    if (tid < 64) {
        cpv[((long)h * 7 + c) * 64 + tid] =
            red[0][tid] + red[1][tid] + red[2][tid] + red[3][tid];
        if (tid == 0) {
            cms[(h * 7 + c) * 2 + 0] = rr[0];
            cms[(h * 7 + c) * 2 + 1] = rr[1];
        }
    }
}

// ---------------------------------------------------------------------------
// CLS proj (inlined LSE combine) + last-block fused residual+LN+fc2 -> out.
// grid 8 x 256 thr.
// ---------------------------------------------------------------------------
__global__ __launch_bounds__(256) void cls_proj_kernel(
    const float* __restrict__ cms, const float* __restrict__ cpv,
    const float* __restrict__ projw, const float* __restrict__ projb,
    float* __restrict__ proj0,
    const float* __restrict__ h0,
    const float* __restrict__ g, const float* __restrict__ b,
    const float* __restrict__ fc2w, const float* __restrict__ fc2b,
    float* __restrict__ out, unsigned* __restrict__ cnt)
{
    __shared__ float av[512], red[4][64];
    __shared__ int isLast;
    const int bk = blockIdx.x, tid = threadIdx.x;
    for (int d = tid; d < 512; d += 256) {
        int h = d >> 6, dd = d & 63;
        float M = -INFINITY;
        #pragma unroll
        for (int c = 0; c < 7; ++c)
            M = fmaxf(M, cms[(h * 7 + c) * 2]);
        float Sx = 0.f, acc = 0.f;
        #pragma unroll
        for (int c = 0; c < 7; ++c) {
            float e = __expf(cms[(h * 7 + c) * 2] - M);
            Sx += cms[(h * 7 + c) * 2 + 1] * e;
            acc += cpv[((long)h * 7 + c) * 64 + dd] * e;
        }
        av[d] = acc / Sx;
    }
    __syncthreads();
    int gg = tid >> 6, n = bk * 64 + (tid & 63);
    float acc = 0.f;
    for (int k = gg * 128; k < gg * 128 + 128; ++k)
        acc = fmaf(av[k], projw[(long)k * 512 + n], acc);
    red[gg][tid & 63] = acc;
    __syncthreads();
    if (tid < 64)
        proj0[bk * 64 + tid] = red[0][tid] + red[1][tid] + red[2][tid]
                               + red[3][tid] + projb[bk * 64 + tid];

    // last-block: residual + LN + fc2 -> out
    __threadfence();
    if (tid == 0) isLast = (atomicAdd(cnt, 1u) == 7u);
    __syncthreads();
    if (!isLast) return;
    __threadfence();

    const int t = tid;
    float v0 = h0[t] + proj0[t];
    float v1 = h0[t + 256] + proj0[t + 256];
    float s = v0 + v1, sq = v0 * v0 + v1 * v1;
    #pragma unroll
    for (int off = 32; off > 0; off >>= 1) {
        s += __shfl_down(s, off);
        sq += __shfl_down(sq, off);
    }
    __shared__ float ps[4], pq[4], pc0[4], pc1[4];
    int w = t >> 6, lane = t & 63;
    if (lane == 0) { ps[w] = s; pq[w] = sq; }
    __syncthreads();
    float Sm = ps[0] + ps[1] + ps[2] + ps[3];
    float Q = pq[0] + pq[1] + pq[2] + pq[3];
    float mean = Sm * (1.f / DIM);
    float var = Q * (1.f / DIM) - mean * mean;
    float inv = rsqrtf(var + LN_EPS);
    float n0 = (v0 - mean) * inv * g[t] + b[t];
    float n1 = (v1 - mean) * inv * g[t + 256] + b[t + 256];
    float c0 = n0 * fc2w[t * 2]     + n1 * fc2w[(t + 256) * 2];
    float c1 = n0 * fc2w[t * 2 + 1] + n1 * fc2w[(t + 256) * 2 + 1];
    #pragma unroll
    for (int off = 32; off > 0; off >>= 1) {
        c0 += __shfl_down(c0, off);
        c1 += __shfl_down(c1, off);
    }
    if (lane == 0) { pc0[w] = c0; pc1[w] = c1; }
    __syncthreads();
    if (t == 0) {
        out[0] = pc0[0] + pc0[1] + pc0[2] + pc0[3] + fc2b[0];
        out[1] = pc1[0] + pc1[1] + pc1[2] + pc1[3] + fc2b[1];
    }
}

// ---------------------------------------------------------------------------
// Mega init: [0,224) fc1 split-K4 (256 K each, total 1024) -> Pp;
// [224,354) CPB angle tables; [354,983) pair -> (angle idx, frac).
// ---------------------------------------------------------------------------
__global__ __launch_bounds__(256) void mega_kernel(
    const float* __restrict__ hin, const float* __restrict__ fc1_w,
    const float* __restrict__ w1_0, const float* __restrict__ b1_0,
    const float* __restrict__ w2_0, const float* __restrict__ b2_0,
    const float* __restrict__ w1_1, const float* __restrict__ b1_1,
    const float* __restrict__ w2_1, const float* __restrict__ b2_1,
    const float* __restrict__ coords,
    float* __restrict__ Pp, float* __restrict__ T,
    int* __restrict__ pm, float* __restrict__ pf)
{
    __shared__ float smem[2176];
    float (*as)[68] = (float(*)[68])smem;
    float (*bs)[68] = (float(*)[68])(smem + 1088);
    float (*red)[64][8] = (float(*)[64][8])smem;
    const int bid = blockIdx.x, tid = threadIdx.x;

    if (bid < 224) {
        int sk = bid / 56, rem = bid % 56;
        int m0 = (rem % 7) * 64, n0 = (rem / 7) * 64;
        int kBeg = sk * 256, kEnd = kBeg + 256;   // 4 x 256 = full K=1024
        float acc[4][4] = {};
        auto loadA = [&](int k0, float r[4]) {
            r[0]=r[1]=r[2]=r[3]=0.f;
            int gm = m0 + (tid >> 2);
            if (gm >= 400) return;
            int gk = k0 + (tid & 3) * 4;
            float4 v = *(const float4*)(hin + (long)gm * 1024 + gk);
            r[0]=v.x; r[1]=v.y; r[2]=v.z; r[3]=v.w;
        };
        auto loadB = [&](int k0, float r[4]) {
            int gk = k0 + (tid >> 4);
            int gn = n0 + (tid & 15) * 4;
            float4 v = *(const float4*)(fc1_w + (long)gk * 512 + gn);
            r[0]=v.x; r[1]=v.y; r[2]=v.z; r[3]=v.w;
        };
        gemm64<false>(kBeg, kEnd, tid, as, bs, acc, loadA, loadB);
        float* C = Pp + (long)sk * PVS;
        const int tx = tid & 15, ty = tid >> 4;
        #pragma unroll
        for (int r = 0; r < 4; ++r) {
            int m = m0 + ty * 4 + r;
            if (m >= 400) continue;
            *(float4*)&C[(long)m * 512 + n0 + tx * 4] =
                make_float4(acc[r][0], acc[r][1], acc[r][2], acc[r][3]);
        }
    } else if (bid < 354) {
        int tb = bid - 224;
        int z = tb / 65, ab = tb % 65;
        const float* w1 = z ? w1_1 : w1_0;
        const float* b1 = z ? b1_1 : b1_0;
        const float* w2 = z ? w2_1 : w2_0;
        const float* b2 = z ? b2_1 : b2_0;
        const int lane = tid & 63, wv = tid >> 6;
        float ca = 0.f, sa = 0.f;
        if (ab != 64) {
            float th = fmaf((float)(ab * 64 + lane),
                            (float)(2.0 * M_PI / CPB_M), -(float)M_PI);
            sincosf(th, &sa, &ca);
        } else if (lane == 0) {
            sincosf((float)M_PI, &sa, &ca);  // wrap row; lanes>0 zero-vec
        }
        float a8[8] = {};
        const int kbeg = wv * 128;
        #pragma unroll 4
        for (int k = kbeg; k < kbeg + 128; ++k) {
            float hk = fmaxf(fmaf(ca, w1[k],
                                  fmaf(sa, w1[512 + k], b1[k])), 0.f);
            #pragma unroll
            for (int h2 = 0; h2 < 8; ++h2)
                a8[h2] = fmaf(hk, w2[k * 8 + h2], a8[h2]);
        }
        #pragma unroll
        for (int h2 = 0; h2 < 8; ++h2) red[wv][lane][h2] = a8[h2];
        __syncthreads();
        if (tid < 64) {
            int aidx = ab * 64 + tid;
            if (aidx <= CPB_M + 1) {
                #pragma unroll
                for (int h2 = 0; h2 < 8; ++h2)
                    T[(long)(z * 8 + h2) * TSTRIDE + aidx] =
                        red[0][tid][h2] + red[1][tid][h2] +
                        red[2][tid][h2] + red[3][tid][h2] + b2[h2];
            }
        }
    } else {
        int p = (bid - 354) * 256 + tid;
        if (p < NP * NP) {
            int i = p / NP, j = p - i * NP;
            float xi = (i == 0) ? 0.f : coords[(i - 1) * 2];
            float yi = (i == 0) ? 0.f : coords[(i - 1) * 2 + 1];
            float xj = (j == 0) ? 0.f : coords[(j - 1) * 2];
            float yj = (j == 0) ? 0.f : coords[(j - 1) * 2 + 1];
            float rx = xi - xj, ry = yi - yj;
            int mm; float fr;
            if (rx == 0.f && ry == 0.f) {
                mm = CPB_M + 1; fr = 0.f;
            } else {
                float x = (atan2f(ry, rx) + 3.14159265358979f)
                          * (float)(CPB_M / (2.0 * M_PI));
                int mi = (int)x;
                fr = x - (float)mi;
                mm = (mi >= CPB_M) ? mi - CPB_M : mi;
            }
            pm[i * 416 + j] = mm;
            pf[i * 416 + j] = fr;
        }
    }
}

// ---------------------------------------------------------------------------
extern "C" void kernel_launch(void* const* d_in, const int* in_sizes, int n_in,
                              void* d_out, int out_size, void* d_ws, size_t ws_size,
                              hipStream_t stream)
{
    const float* coords = (const float*)d_in[1];
    float* ws = (float*)d_ws;
    float* h0   = ws;                    ws += 401L * 512;
    float* xln  = ws;                    ws += 401L * 512;
    float* PO   = ws;                    ws += 7L * PVS;   // flash O-partials
    float* T    = ws;                    ws += 16L * TSTRIDE;
    int*   pm   = (int*)ws;              ws += 401L * 416;
    float* pf   = ws;                    ws += 401L * 416;
    float* kv   = ws;                    ws += 401L * 1024; // layer-2 K,V dense
    float* qkv  = ws;                    ws += 401L * 1536; // layer-1 dense
    float* Pp   = ws;                    ws += 8L * PVS;   // fc1(K4)/proj(K8)
    float* proj0 = ws;                   ws += 512;
    float* cms  = ws;                    ws += 8L * 7 * 2;
    float* cpv  = ws;                    ws += 8L * 7 * 64;
    float* Pml  = ws;                    ws += 8L * 401 * 7 * 2;
    unsigned* cnt = (unsigned*)ws;       ws += 16;

    // phase 0: fc1 (split-K4) + both CPB angle tables + pair->angle map
    mega_kernel<<<983, 256, 0, stream>>>(
        (const float*)d_in[0], (const float*)d_in[2],
        (const float*)d_in[7],  (const float*)d_in[8],
        (const float*)d_in[9],  (const float*)d_in[10],
        (const float*)d_in[17], (const float*)d_in[18],
        (const float*)d_in[19], (const float*)d_in[20],
        coords, Pp, T, pm, pf);

    // fc1 reduce + relu + cls + LN(l1) -> h0, xln
    rowfuse_kernel<<<401, 256, 0, stream>>>(
        Pp, PVS, 4, 1, (const float*)d_in[3], 1, nullptr,
        (const float*)d_in[4], h0,
        (const float*)d_in[5], (const float*)d_in[6], xln);

    // -------- layer 1: dense qkv GEMM (bias fused), flash, proj --------
    gemm_bias_kernel<<<dim3(7, 24), 256, 0, stream>>>(
        xln, (const float*)d_in[11], 1536, (const float*)d_in[12],
        qkv, 1536);
    flash_kernel<<<dim3(7, 7, 8), 256, 0, stream>>>(
        qkv, pm, pf, T, PO, Pml);
    proj_kernel<<<dim3(7, 8, 8), 256, 0, stream>>>(
        PO, Pml, (const float*)d_in[13], Pp);
    rowfuse_kernel<<<401, 256, 0, stream>>>(
        Pp, PVS, 8, 0, (const float*)d_in[14], 0, h0, nullptr, h0,
        (const float*)d_in[15], (const float*)d_in[16], xln);

    // -------- layer 2: dense K,V GEMM (bias fused), CLS flash-decode ----
    gemm_bias_kernel<<<dim3(7, 16), 256, 0, stream>>>(
        xln, (const float*)d_in[21] + 512, 1536, (const float*)d_in[22] + 512,
        kv, 1024);
    cls_decode_kernel<<<dim3(8, 7), 256, 0, stream>>>(
        xln, (const float*)d_in[21], kv, (const float*)d_in[22],
        pm, pf, T + 8L * TSTRIDE, cms, cpv, cnt);
    cls_proj_kernel<<<8, 256, 0, stream>>>(
        cms, cpv, (const float*)d_in[23], (const float*)d_in[24], proj0,
        h0, (const float*)d_in[25], (const float*)d_in[26],
        (const float*)d_in[27], (const float*)d_in[28], (float*)d_out, cnt);
}

// Round 6
// 237.331 us; speedup vs baseline: 9.7586x; 1.0225x over previous
//
#include <hip/hip_runtime.h>
#include <math.h>

#define NP 401            // tokens incl. CLS (400 patches, side=20, add=0)
#define DIM 512
#define LN_EPS 1e-5f
#define ATT_SCALE 0.125f
#define CPB_M 4096        // angle-table resolution (interp err ~2e-5 << tol)
#define TSTRIDE (CPB_M + 64)
#define PQS (401L * 1536) // layer-1 qkv partial slice stride
#define PKS (401L * 1024) // layer-2 kv partial slice stride
#define PVS (401L * 512)  // fc1 / pv / proj partial slice stride

// ---------------------------------------------------------------------------
// 64x64-tile GEMM body: 256 thr, 4x4 micro-tile, K-chunk 16, register
// double-buffered staging via caller-supplied loaders.
// ---------------------------------------------------------------------------
template<bool TB, typename LA, typename LB>
__device__ __forceinline__ void gemm64(
    int kBeg, int kEnd, int tid,
    float (*as)[68], float (*bs)[68], float (&acc)[4][4],
    LA&& loadA, LB&& loadB)
{
    float aR[4], bR[4];
    loadA(kBeg, aR);
    loadB(kBeg, bR);
    for (int k0 = kBeg; k0 < kEnd; k0 += 16) {
        const int arow = tid >> 2, aq = tid & 3;
        as[aq * 4 + 0][arow] = aR[0];
        as[aq * 4 + 1][arow] = aR[1];
        as[aq * 4 + 2][arow] = aR[2];
        as[aq * 4 + 3][arow] = aR[3];
        if (!TB) {
            *(float4*)&bs[tid >> 4][(tid & 15) * 4] =
                make_float4(bR[0], bR[1], bR[2], bR[3]);
        } else {
            bs[aq * 4 + 0][arow] = bR[0];
            bs[aq * 4 + 1][arow] = bR[1];
            bs[aq * 4 + 2][arow] = bR[2];
            bs[aq * 4 + 3][arow] = bR[3];
        }
        __syncthreads();
        float nA[4] = {0.f,0.f,0.f,0.f}, nB[4] = {0.f,0.f,0.f,0.f};
        if (k0 + 16 < kEnd) { loadA(k0 + 16, nA); loadB(k0 + 16, nB); }
        const int tx = tid & 15, ty = tid >> 4;
        #pragma unroll
        for (int kk = 0; kk < 16; ++kk) {
            float4 a4 = *(const float4*)&as[kk][ty * 4];
            float4 b4 = *(const float4*)&bs[kk][tx * 4];
            float av[4] = {a4.x, a4.y, a4.z, a4.w};
            float bv[4] = {b4.x, b4.y, b4.z, b4.w};
            #pragma unroll
            for (int r = 0; r < 4; ++r)
                #pragma unroll
                for (int c = 0; c < 4; ++c)
                    acc[r][c] = fmaf(av[r], bv[c], acc[r][c]);
        }
        __syncthreads();
        #pragma unroll
        for (int j = 0; j < 4; ++j) { aR[j] = nA[j]; bR[j] = nB[j]; }
    }
}

// ---------------------------------------------------------------------------
// Generic split-K GEMM: P[sk] = A[:, slice] @ B[slice, :]  (raw partials).
// A is 401 x 512 (lda param), B ldb. Consumers fold the slice sum.
// ---------------------------------------------------------------------------
__global__ __launch_bounds__(256) void gemm_split_kernel(
    const float* __restrict__ A, int lda,
    const float* __restrict__ B, int ldb,
    float* __restrict__ P, int ldc, long slice,
    int M, int N, int K, int skN)
{
    __shared__ float as[16][68], bs[16][68];
    const int tid = threadIdx.x;
    const int m0 = blockIdx.x * 64, n0 = blockIdx.y * 64;
    const int sk = blockIdx.z;
    const int KS = ((K + skN * 16 - 1) / (skN * 16)) * 16;
    const int kBeg = sk * KS;
    const int kEnd = (kBeg + KS < K) ? kBeg + KS : K;
    float acc[4][4] = {};

    auto loadA = [&](int k0, float r[4]) {
        r[0] = r[1] = r[2] = r[3] = 0.f;
        int gm = m0 + (tid >> 2);
        if (gm >= M) return;
        int gk = k0 + (tid & 3) * 4;
        const float* p = A + (long)gm * lda + gk;
        if (gk + 3 < kEnd) {
            float4 v = *(const float4*)p;
            r[0] = v.x; r[1] = v.y; r[2] = v.z; r[3] = v.w;
        } else {
            #pragma unroll
            for (int j = 0; j < 4; ++j) if (gk + j < kEnd) r[j] = p[j];
        }
    };
    auto loadB = [&](int k0, float r[4]) {
        r[0] = r[1] = r[2] = r[3] = 0.f;
        int gk = k0 + (tid >> 4);
        if (gk >= kEnd) return;
        int gn = n0 + (tid & 15) * 4;
        const float* p = B + (long)gk * ldb + gn;
        float4 v = *(const float4*)p;
        r[0] = v.x; r[1] = v.y; r[2] = v.z; r[3] = v.w;
    };
    if (kBeg < kEnd)
        gemm64<false>(kBeg, kEnd, tid, as, bs, acc, loadA, loadB);

    float* C = P + (long)sk * slice;
    const int tx = tid & 15, ty = tid >> 4;
    #pragma unroll
    for (int r = 0; r < 4; ++r) {
        int m = m0 + ty * 4 + r;
        if (m >= M) continue;
        *(float4*)&C[(long)m * ldc + n0 + tx * 4] =
            make_float4(acc[r][0], acc[r][1], acc[r][2], acc[r][3]);
    }
}

// ---------------------------------------------------------------------------
// Fused flash attention tile (layer 1): one block = one (m-tile, kv-tile,
// head). Q/K/V are read as sum of 4 qkv split-K partials + bias (fold the
// reduce into the loaders — all L2-hot). QK^T via gemm64, CPB bias interp,
// tile-local softmax, P·V through LDS. grid (7, 7, 8).
// ---------------------------------------------------------------------------
__global__ __launch_bounds__(256) void flash_kernel(
    const float* __restrict__ Pq,   // 4 slices, stride PQS, ldc 1536
    const float* __restrict__ qkvb,
    const int* __restrict__ pm, const float* __restrict__ pf,
    const float* __restrict__ T,
    float* __restrict__ PO,        // (7, 401, 512) chunk partials
    float* __restrict__ Pml)       // (8, 401, 7, 2)
{
    __shared__ float as[16][68], bs[16][68];
    __shared__ float pT[64][68];   // P transposed: [key][row]
    __shared__ float vs[64][68];   // V tile: [key][dim]
    const int tid = threadIdx.x;
    const int m0 = blockIdx.x * 64, nb = blockIdx.y, h = blockIdx.z;
    const int n0 = nb * 64;
    float acc[4][4] = {};

    // V tile -> registers early (4-slice sum + bias; overlaps the QK gemm)
    float vreg[4][4];
    {
        int key = n0 + (tid >> 2);
        int d0 = (tid & 3) * 16;
        if (key <= 400) {
            long base = (long)key * 1536 + 1024 + h * 64 + d0;
            #pragma unroll
            for (int i = 0; i < 4; ++i) {
                float4 v0 = *(const float4*)(Pq + base + i * 4);
                float4 v1 = *(const float4*)(Pq + PQS + base + i * 4);
                float4 v2 = *(const float4*)(Pq + 2 * PQS + base + i * 4);
                float4 v3 = *(const float4*)(Pq + 3 * PQS + base + i * 4);
                float4 bb = *(const float4*)(qkvb + 1024 + h * 64 + d0 + i * 4);
                vreg[i][0] = v0.x + v1.x + v2.x + v3.x + bb.x;
                vreg[i][1] = v0.y + v1.y + v2.y + v3.y + bb.y;
                vreg[i][2] = v0.z + v1.z + v2.z + v3.z + bb.z;
                vreg[i][3] = v0.w + v1.w + v2.w + v3.w + bb.w;
            }
        } else {
            #pragma unroll
            for (int i = 0; i < 4; ++i)
                vreg[i][0] = vreg[i][1] = vreg[i][2] = vreg[i][3] = 0.f;
        }
    }

    auto loadQ = [&](int k0, float r[4]) {
        int gm = m0 + (tid >> 2);
        if (gm > 400) { r[0]=r[1]=r[2]=r[3]=0.f; return; }
        int gk = k0 + (tid & 3) * 4;
        long base = (long)gm * 1536 + h * 64 + gk;
        float4 v0 = *(const float4*)(Pq + base);
        float4 v1 = *(const float4*)(Pq + PQS + base);
        float4 v2 = *(const float4*)(Pq + 2 * PQS + base);
        float4 v3 = *(const float4*)(Pq + 3 * PQS + base);
        float4 bb = *(const float4*)(qkvb + h * 64 + gk);
        r[0] = v0.x + v1.x + v2.x + v3.x + bb.x;
        r[1] = v0.y + v1.y + v2.y + v3.y + bb.y;
        r[2] = v0.z + v1.z + v2.z + v3.z + bb.z;
        r[3] = v0.w + v1.w + v2.w + v3.w + bb.w;
    };
    auto loadK = [&](int k0, float r[4]) {
        int gn = n0 + (tid >> 2);
        if (gn > 400) { r[0]=r[1]=r[2]=r[3]=0.f; return; }
        int gk = k0 + (tid & 3) * 4;
        long base = (long)gn * 1536 + 512 + h * 64 + gk;
        float4 v0 = *(const float4*)(Pq + base);
        float4 v1 = *(const float4*)(Pq + PQS + base);
        float4 v2 = *(const float4*)(Pq + 2 * PQS + base);
        float4 v3 = *(const float4*)(Pq + 3 * PQS + base);
        float4 bb = *(const float4*)(qkvb + 512 + h * 64 + gk);
        r[0] = v0.x + v1.x + v2.x + v3.x + bb.x;
        r[1] = v0.y + v1.y + v2.y + v3.y + bb.y;
        r[2] = v0.z + v1.z + v2.z + v3.z + bb.z;
        r[3] = v0.w + v1.w + v2.w + v3.w + bb.w;
    };
    gemm64<true>(0, 64, tid, as, bs, acc, loadQ, loadK);
    // gemm64 exits right after a __syncthreads(): safe to write pT/vs now.

    // V regs -> LDS
    {
        int key = tid >> 2, d0 = (tid & 3) * 16;
        #pragma unroll
        for (int i = 0; i < 4; ++i)
            *(float4*)&vs[key][d0 + i * 4] =
                make_float4(vreg[i][0], vreg[i][1], vreg[i][2], vreg[i][3]);
    }

    // CPB bias + tile-local softmax; keep p in regs for transposed store
    const int tx = tid & 15, ty = tid >> 4;
    const float* Tt = T + (long)h * TSTRIDE;
    float p[4][4];
    #pragma unroll
    for (int r = 0; r < 4; ++r) {
        int i = m0 + ty * 4 + r;
        float sv[4];
        #pragma unroll
        for (int c = 0; c < 4; ++c) {
            int j = n0 + tx * 4 + c;
            if (i <= 400 && j <= 400) {
                int id = i * 416 + j;
                int mm = pm[id];
                float fr = pf[id];
                float t0 = Tt[mm], t1 = Tt[mm + 1];
                sv[c] = fmaf(acc[r][c], ATT_SCALE, fmaf(fr, t1 - t0, t0));
            } else {
                sv[c] = -INFINITY;
            }
        }
        float cmax = fmaxf(fmaxf(sv[0], sv[1]), fmaxf(sv[2], sv[3]));
        cmax = fmaxf(cmax, __shfl_xor(cmax, 1));
        cmax = fmaxf(cmax, __shfl_xor(cmax, 2));
        cmax = fmaxf(cmax, __shfl_xor(cmax, 4));
        cmax = fmaxf(cmax, __shfl_xor(cmax, 8));
        const bool rowok = (i <= 400);
        #pragma unroll
        for (int c = 0; c < 4; ++c)
            p[r][c] = rowok ? __expf(sv[c] - cmax) : 0.f;
        float cs = p[r][0] + p[r][1] + p[r][2] + p[r][3];
        cs += __shfl_xor(cs, 1);
        cs += __shfl_xor(cs, 2);
        cs += __shfl_xor(cs, 4);
        cs += __shfl_xor(cs, 8);
        if (tx == 0 && rowok) {
            long o = ((long)(h * 401 + i) * 7 + nb) * 2;
            Pml[o] = cmax;
            Pml[o + 1] = cs;
        }
    }
    // transposed store: pT[key][row], float4 over rows (contiguous)
    #pragma unroll
    for (int c = 0; c < 4; ++c)
        *(float4*)&pT[tx * 4 + c][ty * 4] =
            make_float4(p[0][c], p[1][c], p[2][c], p[3][c]);
    __syncthreads();

    // P·V: o[r][c] += sum_k pT[k][row] * vs[k][dim]; LDS-only operands
    float o[4][4] = {};
    #pragma unroll 16
    for (int kk = 0; kk < 64; ++kk) {
        float4 a4 = *(const float4*)&pT[kk][ty * 4];
        float4 b4 = *(const float4*)&vs[kk][tx * 4];
        float av[4] = {a4.x, a4.y, a4.z, a4.w};
        float bv[4] = {b4.x, b4.y, b4.z, b4.w};
        #pragma unroll
        for (int r = 0; r < 4; ++r)
            #pragma unroll
            for (int c = 0; c < 4; ++c)
                o[r][c] = fmaf(av[r], bv[c], o[r][c]);
    }

    float* C = PO + (long)nb * PVS;
    #pragma unroll
    for (int r = 0; r < 4; ++r) {
        int m = m0 + ty * 4 + r;
        if (m > 400) continue;
        *(float4*)&C[(long)m * 512 + h * 64 + tx * 4] =
            make_float4(o[r][0], o[r][1], o[r][2], o[r][3]);
    }
}

// ---------------------------------------------------------------------------
// proj (layer 1), split-K8 (one head per z), LSE combine of the 7 flash
// O-partials folded into the A-loader. grid (7,8,8).
// ---------------------------------------------------------------------------
__global__ __launch_bounds__(256) void proj_kernel(
    const float* __restrict__ PO, const float* __restrict__ Pml,
    const float* __restrict__ projw, float* __restrict__ Pp)
{
    __shared__ float as[16][68], bs[16][68];
    __shared__ float wls[64][8];
    const int tid = threadIdx.x;
    const int m0 = blockIdx.x * 64, n0 = blockIdx.y * 64, sk = blockIdx.z;
    const int kBeg = sk * 64, kEnd = kBeg + 64;
    float acc[4][4] = {};

    // per-row LSE merge weights for head sk
    if (tid < 64) {
        int row = m0 + tid;
        if (row <= 400) {
            const float* q = Pml + ((long)(sk * 401 + row) * 7) * 2;
            float M = -INFINITY;
            #pragma unroll
            for (int c = 0; c < 7; ++c) M = fmaxf(M, q[c * 2]);
            float D = 0.f;
            #pragma unroll
            for (int c = 0; c < 7; ++c) D += q[c * 2 + 1] * __expf(q[c * 2] - M);
            float iD = 1.f / D;
            #pragma unroll
            for (int c = 0; c < 7; ++c) wls[tid][c] = __expf(q[c * 2] - M) * iD;
        } else {
            #pragma unroll
            for (int c = 0; c < 7; ++c) wls[tid][c] = 0.f;
        }
    }
    __syncthreads();

    auto loadA = [&](int k0, float r4[4]) {
        r4[0] = r4[1] = r4[2] = r4[3] = 0.f;
        int lm = tid >> 2, gm = m0 + lm;
        if (gm > 400) return;
        int gk = k0 + (tid & 3) * 4;
        #pragma unroll
        for (int s = 0; s < 7; ++s) {
            float4 v = *(const float4*)(PO + (long)s * PVS + (long)gm * 512 + gk);
            float w = wls[lm][s];
            r4[0] = fmaf(w, v.x, r4[0]);
            r4[1] = fmaf(w, v.y, r4[1]);
            r4[2] = fmaf(w, v.z, r4[2]);
            r4[3] = fmaf(w, v.w, r4[3]);
        }
    };
    auto loadB = [&](int k0, float r[4]) {
        int gk = k0 + (tid >> 4);
        int gn = n0 + (tid & 15) * 4;
        float4 v = *(const float4*)(projw + (long)gk * 512 + gn);
        r[0]=v.x; r[1]=v.y; r[2]=v.z; r[3]=v.w;
    };
    gemm64<false>(kBeg, kEnd, tid, as, bs, acc, loadA, loadB);

    float* C = Pp + (long)sk * PVS;
    const int tx = tid & 15, ty = tid >> 4;
    #pragma unroll
    for (int r = 0; r < 4; ++r) {
        int m = m0 + ty * 4 + r;
        if (m > 400) continue;
        *(float4*)&C[(long)m * 512 + n0 + tx * 4] =
            make_float4(acc[r][0], acc[r][1], acc[r][2], acc[r][3]);
    }
}

// ---------------------------------------------------------------------------
// Per-row split-K reduce + epilogue + LayerNorm. grid 401.
// ---------------------------------------------------------------------------
__global__ __launch_bounds__(256) void rowfuse_kernel(
    const float* __restrict__ P, long slice, int skN, int rowOff,
    const float* __restrict__ bias, int doRelu,
    const float* __restrict__ resid, const float* __restrict__ cls,
    float* __restrict__ h0,
    const float* __restrict__ g, const float* __restrict__ b,
    float* __restrict__ xln)
{
    const int r = blockIdx.x, t = threadIdx.x;
    float v0, v1;
    if (cls && r == 0) {
        v0 = cls[t]; v1 = cls[t + 256];
    } else {
        const float* p = P + (long)(r - rowOff) * DIM;
        v0 = bias[t]; v1 = bias[t + 256];
        for (int k = 0; k < skN; ++k) {
            v0 += p[(long)k * slice + t];
            v1 += p[(long)k * slice + t + 256];
        }
        if (resid) {
            v0 += resid[(long)r * DIM + t];
            v1 += resid[(long)r * DIM + t + 256];
        }
        if (doRelu) { v0 = fmaxf(v0, 0.f); v1 = fmaxf(v1, 0.f); }
    }
    h0[(long)r * DIM + t] = v0;
    h0[(long)r * DIM + t + 256] = v1;

    float s = v0 + v1, sq = v0 * v0 + v1 * v1;
    #pragma unroll
    for (int off = 32; off > 0; off >>= 1) {
        s += __shfl_down(s, off);
        sq += __shfl_down(sq, off);
    }
    __shared__ float ps[4], pq[4];
    int w = t >> 6, lane = t & 63;
    if (lane == 0) { ps[w] = s; pq[w] = sq; }
    __syncthreads();
    float Sm = ps[0] + ps[1] + ps[2] + ps[3];
    float Q = pq[0] + pq[1] + pq[2] + pq[3];
    float mean = Sm * (1.f / DIM);
    float var = Q * (1.f / DIM) - mean * mean;
    float inv = rsqrtf(var + LN_EPS);
    xln[(long)r * DIM + t]       = (v0 - mean) * inv * g[t] + b[t];
    xln[(long)r * DIM + t + 256] = (v1 - mean) * inv * g[t + 256] + b[t + 256];
}

// ---------------------------------------------------------------------------
// CLS flash-decode (layer 2): grid (8 heads, 7 key-chunks of 64).
// q0 inline from xln row 0; K/V from 4 kv split-K partials + bias inline.
// Also zeroes the cls_proj completion counter (block (0,0)).
// ---------------------------------------------------------------------------
__global__ __launch_bounds__(256) void cls_decode_kernel(
    const float* __restrict__ xln, const float* __restrict__ qkvw,
    const float* __restrict__ Pkv, const float* __restrict__ qkvb,
    const int* __restrict__ pm, const float* __restrict__ pf,
    const float* __restrict__ T,
    float* __restrict__ cms, float* __restrict__ cpv,
    unsigned* __restrict__ cnt)
{
    const int h = blockIdx.x, c = blockIdx.y, tid = threadIdx.x;
    const int kBeg = c * 64;
    __shared__ float q0[64], scraw[64], p[64], red[4][64], rr[2];

    if (h == 0 && c == 0 && tid == 0) *cnt = 0u;   // init for cls_proj

    // q0[d] = sum_k xln[0][k] * Wq[k][h*64+d] + bq[h*64+d]; 4-wave k-split
    {
        int d = tid & 63, w4 = tid >> 6;
        const float* col = qkvw + h * 64 + d;
        float acc = 0.f;
        for (int k = w4 * 128; k < w4 * 128 + 128; ++k)
            acc = fmaf(xln[k], col[(long)k * 1536], acc);
        red[w4][d] = acc;
    }
    __syncthreads();
    if (tid < 64)
        q0[tid] = red[0][tid] + red[1][tid] + red[2][tid] + red[3][tid]
                  + qkvb[h * 64 + tid];
    __syncthreads();

    // scores: key k = tid>>2 (4 lanes/key, 16 dims each), shuffle-reduce
    {
        int k = tid >> 2, q = tid & 3;
        int j = kBeg + k;
        float dot = 0.f;
        if (j < NP) {
            long base = (long)j * 1024 + h * 64 + q * 16;   // K cols 0..512
            #pragma unroll
            for (int d = 0; d < 16; d += 4) {
                float4 x0 = *(const float4*)(Pkv + base + d);
                float4 x1 = *(const float4*)(Pkv + PKS + base + d);
                float4 x2 = *(const float4*)(Pkv + 2 * PKS + base + d);
                float4 x3 = *(const float4*)(Pkv + 3 * PKS + base + d);
                float4 bb = *(const float4*)(qkvb + 512 + h * 64 + q * 16 + d);
                float4 qq = *(const float4*)(q0 + q * 16 + d);
                dot = fmaf(qq.x, x0.x + x1.x + x2.x + x3.x + bb.x, dot);
                dot = fmaf(qq.y, x0.y + x1.y + x2.y + x3.y + bb.y, dot);
                dot = fmaf(qq.z, x0.z + x1.z + x2.z + x3.z + bb.z, dot);
                dot = fmaf(qq.w, x0.w + x1.w + x2.w + x3.w + bb.w, dot);
            }
        }
        dot += __shfl_down(dot, 2);
        dot += __shfl_down(dot, 1);
        if (q == 0) scraw[k] = dot;
    }
    __syncthreads();

    // bias + local softmax on wave 0
    if (tid < 64) {
        int j = kBeg + tid;
        float s;
        if (j < NP) {
            int mm = pm[j];                   // row 0 of pair map
            float fr = pf[j];
            const float* Tt = T + (long)h * TSTRIDE;
            float t0 = Tt[mm], t1 = Tt[mm + 1];
            s = fmaf(scraw[tid], ATT_SCALE, fmaf(fr, t1 - t0, t0));
        } else {
            s = -INFINITY;
        }
        float m = s;
        #pragma unroll
        for (int off = 32; off > 0; off >>= 1)
            m = fmaxf(m, __shfl_xor(m, off));
        float e = (j < NP) ? __expf(s - m) : 0.f;
        float sum = e;
        #pragma unroll
        for (int off = 32; off > 0; off >>= 1)
            sum += __shfl_xor(sum, off);
        p[tid] = e;
        if (tid == 0) { rr[0] = m; rr[1] = sum; }
    }
    __syncthreads();

    // partial PV: d = lane, wave w handles keys k ≡ w (mod 4)
    {
        int w = tid >> 6, d = tid & 63;
        float vb = qkvb[1024 + h * 64 + d];
        float acc = 0.f;
        for (int k = w; k < 64; k += 4) {
            int j = kBeg + k;
            if (j >= NP) break;
            long o = (long)j * 1024 + 512 + h * 64 + d;     // V cols 512..1024
            float v = Pkv[o] + Pkv[PKS + o] + Pkv[2 * PKS + o]
                      + Pkv[3 * PKS + o] + vb;
            acc = fmaf(p[k], v, acc);
        }
        red[w][d] = acc;
    }
    __syncthreads();
    if (tid < 64) {
        cpv[((long)h * 7 + c) * 64 + tid] =
            red[0][tid] + red[1][tid] + red[2][tid] + red[3][tid];
        if (tid == 0) {
            cms[(h * 7 + c) * 2 + 0] = rr[0];
            cms[(h * 7 + c) * 2 + 1] = rr[1];
        }
    }
}

// ---------------------------------------------------------------------------
// CLS proj (inlined LSE combine) + last-block fused residual+LN+fc2 -> out.
// grid 8 x 256 thr.
// ---------------------------------------------------------------------------
__global__ __launch_bounds__(256) void cls_proj_kernel(
    const float* __restrict__ cms, const float* __restrict__ cpv,
    const float* __restrict__ projw, const float* __restrict__ projb,
    float* __restrict__ proj0,
    const float* __restrict__ h0,
    const float* __restrict__ g, const float* __restrict__ b,
    const float* __restrict__ fc2w, const float* __restrict__ fc2b,
    float* __restrict__ out, unsigned* __restrict__ cnt)
{
    __shared__ float av[512], red[4][64];
    __shared__ int isLast;
    const int bk = blockIdx.x, tid = threadIdx.x;
    for (int d = tid; d < 512; d += 256) {
        int h = d >> 6, dd = d & 63;
        float M = -INFINITY;
        #pragma unroll
        for (int c = 0; c < 7; ++c)
            M = fmaxf(M, cms[(h * 7 + c) * 2]);
        float Sx = 0.f, acc = 0.f;
        #pragma unroll
        for (int c = 0; c < 7; ++c) {
            float e = __expf(cms[(h * 7 + c) * 2] - M);
            Sx += cms[(h * 7 + c) * 2 + 1] * e;
            acc += cpv[((long)h * 7 + c) * 64 + dd] * e;
        }
        av[d] = acc / Sx;
    }
    __syncthreads();
    int gg = tid >> 6, n = bk * 64 + (tid & 63);
    float acc = 0.f;
    for (int k = gg * 128; k < gg * 128 + 128; ++k)
        acc = fmaf(av[k], projw[(long)k * 512 + n], acc);
    red[gg][tid & 63] = acc;
    __syncthreads();
    if (tid < 64)
        proj0[bk * 64 + tid] = red[0][tid] + red[1][tid] + red[2][tid]
                               + red[3][tid] + projb[bk * 64 + tid];

    // last-block: residual + LN + fc2 -> out
    __threadfence();
    if (tid == 0) isLast = (atomicAdd(cnt, 1u) == 7u);
    __syncthreads();
    if (!isLast) return;
    __threadfence();

    const int t = tid;
    float v0 = h0[t] + proj0[t];
    float v1 = h0[t + 256] + proj0[t + 256];
    float s = v0 + v1, sq = v0 * v0 + v1 * v1;
    #pragma unroll
    for (int off = 32; off > 0; off >>= 1) {
        s += __shfl_down(s, off);
        sq += __shfl_down(sq, off);
    }
    __shared__ float ps[4], pq[4], pc0[4], pc1[4];
    int w = t >> 6, lane = t & 63;
    if (lane == 0) { ps[w] = s; pq[w] = sq; }
    __syncthreads();
    float Sm = ps[0] + ps[1] + ps[2] + ps[3];
    float Q = pq[0] + pq[1] + pq[2] + pq[3];
    float mean = Sm * (1.f / DIM);
    float var = Q * (1.f / DIM) - mean * mean;
    float inv = rsqrtf(var + LN_EPS);
    float n0 = (v0 - mean) * inv * g[t] + b[t];
    float n1 = (v1 - mean) * inv * g[t + 256] + b[t + 256];
    float c0 = n0 * fc2w[t * 2]     + n1 * fc2w[(t + 256) * 2];
    float c1 = n0 * fc2w[t * 2 + 1] + n1 * fc2w[(t + 256) * 2 + 1];
    #pragma unroll
    for (int off = 32; off > 0; off >>= 1) {
        c0 += __shfl_down(c0, off);
        c1 += __shfl_down(c1, off);
    }
    if (lane == 0) { pc0[w] = c0; pc1[w] = c1; }
    __syncthreads();
    if (t == 0) {
        out[0] = pc0[0] + pc0[1] + pc0[2] + pc0[3] + fc2b[0];
        out[1] = pc1[0] + pc1[1] + pc1[2] + pc1[3] + fc2b[1];
    }
}

// ---------------------------------------------------------------------------
// Mega init: [0,448) fc1 split-K8 (128 K each, total 1024) -> Pp;
// [448,578) CPB angle tables; [578,1207) pair -> (angle idx, frac).
// ---------------------------------------------------------------------------
__global__ __launch_bounds__(256) void mega_kernel(
    const float* __restrict__ hin, const float* __restrict__ fc1_w,
    const float* __restrict__ w1_0, const float* __restrict__ b1_0,
    const float* __restrict__ w2_0, const float* __restrict__ b2_0,
    const float* __restrict__ w1_1, const float* __restrict__ b1_1,
    const float* __restrict__ w2_1, const float* __restrict__ b2_1,
    const float* __restrict__ coords,
    float* __restrict__ Pp, float* __restrict__ T,
    int* __restrict__ pm, float* __restrict__ pf)
{
    __shared__ float smem[2176];
    float (*as)[68] = (float(*)[68])smem;
    float (*bs)[68] = (float(*)[68])(smem + 1088);
    float (*red)[64][8] = (float(*)[64][8])smem;
    const int bid = blockIdx.x, tid = threadIdx.x;

    if (bid < 448) {
        int sk = bid / 56, rem = bid % 56;
        int m0 = (rem % 7) * 64, n0 = (rem / 7) * 64;
        int kBeg = sk * 128, kEnd = kBeg + 128;   // 8 x 128 = full K=1024
        float acc[4][4] = {};
        auto loadA = [&](int k0, float r[4]) {
            r[0]=r[1]=r[2]=r[3]=0.f;
            int gm = m0 + (tid >> 2);
            if (gm >= 400) return;
            int gk = k0 + (tid & 3) * 4;
            float4 v = *(const float4*)(hin + (long)gm * 1024 + gk);
            r[0]=v.x; r[1]=v.y; r[2]=v.z; r[3]=v.w;
        };
        auto loadB = [&](int k0, float r[4]) {
            int gk = k0 + (tid >> 4);
            int gn = n0 + (tid & 15) * 4;
            float4 v = *(const float4*)(fc1_w + (long)gk * 512 + gn);
            r[0]=v.x; r[1]=v.y; r[2]=v.z; r[3]=v.w;
        };
        gemm64<false>(kBeg, kEnd, tid, as, bs, acc, loadA, loadB);
        float* C = Pp + (long)sk * PVS;
        const int tx = tid & 15, ty = tid >> 4;
        #pragma unroll
        for (int r = 0; r < 4; ++r) {
            int m = m0 + ty * 4 + r;
            if (m >= 400) continue;
            *(float4*)&C[(long)m * 512 + n0 + tx * 4] =
                make_float4(acc[r][0], acc[r][1], acc[r][2], acc[r][3]);
        }
    } else if (bid < 578) {
        int tb = bid - 448;
        int z = tb / 65, ab = tb % 65;
        const float* w1 = z ? w1_1 : w1_0;
        const float* b1 = z ? b1_1 : b1_0;
        const float* w2 = z ? w2_1 : w2_0;
        const float* b2 = z ? b2_1 : b2_0;
        const int lane = tid & 63, wv = tid >> 6;
        float ca = 0.f, sa = 0.f;
        if (ab != 64) {
            float th = fmaf((float)(ab * 64 + lane),
                            (float)(2.0 * M_PI / CPB_M), -(float)M_PI);
            sincosf(th, &sa, &ca);
        } else if (lane == 0) {
            sincosf((float)M_PI, &sa, &ca);  // wrap row; lanes>0 zero-vec
        }
        float a8[8] = {};
        const int kbeg = wv * 128;
        #pragma unroll 4
        for (int k = kbeg; k < kbeg + 128; ++k) {
            float hk = fmaxf(fmaf(ca, w1[k],
                                  fmaf(sa, w1[512 + k], b1[k])), 0.f);
            #pragma unroll
            for (int h2 = 0; h2 < 8; ++h2)
                a8[h2] = fmaf(hk, w2[k * 8 + h2], a8[h2]);
        }
        #pragma unroll
        for (int h2 = 0; h2 < 8; ++h2) red[wv][lane][h2] = a8[h2];
        __syncthreads();
        if (tid < 64) {
            int aidx = ab * 64 + tid;
            if (aidx <= CPB_M + 1) {
                #pragma unroll
                for (int h2 = 0; h2 < 8; ++h2)
                    T[(long)(z * 8 + h2) * TSTRIDE + aidx] =
                        red[0][tid][h2] + red[1][tid][h2] +
                        red[2][tid][h2] + red[3][tid][h2] + b2[h2];
            }
        }
    } else {
        int p = (bid - 578) * 256 + tid;
        if (p < NP * NP) {
            int i = p / NP, j = p - i * NP;
            float xi = (i == 0) ? 0.f : coords[(i - 1) * 2];
            float yi = (i == 0) ? 0.f : coords[(i - 1) * 2 + 1];
            float xj = (j == 0) ? 0.f : coords[(j - 1) * 2];
            float yj = (j == 0) ? 0.f : coords[(j - 1) * 2 + 1];
            float rx = xi - xj, ry = yi - yj;
            int mm; float fr;
            if (rx == 0.f && ry == 0.f) {
                mm = CPB_M + 1; fr = 0.f;
            } else {
                float x = (atan2f(ry, rx) + 3.14159265358979f)
                          * (float)(CPB_M / (2.0 * M_PI));
                int mi = (int)x;
                fr = x - (float)mi;
                mm = (mi >= CPB_M) ? mi - CPB_M : mi;
            }
            pm[i * 416 + j] = mm;
            pf[i * 416 + j] = fr;
        }
    }
}

// ---------------------------------------------------------------------------
extern "C" void kernel_launch(void* const* d_in, const int* in_sizes, int n_in,
                              void* d_out, int out_size, void* d_ws, size_t ws_size,
                              hipStream_t stream)
{
    const float* coords = (const float*)d_in[1];
    float* ws = (float*)d_ws;
    float* h0   = ws;                    ws += 401L * 512;
    float* xln  = ws;                    ws += 401L * 512;
    float* PO   = ws;                    ws += 7L * PVS;   // flash O-partials
    float* T    = ws;                    ws += 16L * TSTRIDE;
    int*   pm   = (int*)ws;              ws += 401L * 416;
    float* pf   = ws;                    ws += 401L * 416;
    float* Pq   = ws;                    ws += 4L * PQS;   // qkv / layer-2 kv partials
    float* Pp   = ws;                    ws += 8L * PVS;   // fc1(K8)/proj(K8)
    float* proj0 = ws;                   ws += 512;
    float* cms  = ws;                    ws += 8L * 7 * 2;
    float* cpv  = ws;                    ws += 8L * 7 * 64;
    float* Pml  = ws;                    ws += 8L * 401 * 7 * 2;
    unsigned* cnt = (unsigned*)ws;       ws += 16;

    // phase 0: fc1 (split-K8) + both CPB angle tables + pair->angle map
    mega_kernel<<<1207, 256, 0, stream>>>(
        (const float*)d_in[0], (const float*)d_in[2],
        (const float*)d_in[7],  (const float*)d_in[8],
        (const float*)d_in[9],  (const float*)d_in[10],
        (const float*)d_in[17], (const float*)d_in[18],
        (const float*)d_in[19], (const float*)d_in[20],
        coords, Pp, T, pm, pf);

    // fc1 reduce + relu + cls + LN(l1) -> h0, xln
    rowfuse_kernel<<<401, 256, 0, stream>>>(
        Pp, PVS, 8, 1, (const float*)d_in[3], 1, nullptr,
        (const float*)d_in[4], h0,
        (const float*)d_in[5], (const float*)d_in[6], xln);

    // -------- layer 1: split-K4 qkv (partials), flash folds sum+bias ------
    gemm_split_kernel<<<dim3(7, 24, 4), 256, 0, stream>>>(
        xln, 512, (const float*)d_in[11], 1536, Pq, 1536, PQS,
        401, 1536, 512, 4);
    flash_kernel<<<dim3(7, 7, 8), 256, 0, stream>>>(
        Pq, (const float*)d_in[12], pm, pf, T, PO, Pml);
    proj_kernel<<<dim3(7, 8, 8), 256, 0, stream>>>(
        PO, Pml, (const float*)d_in[13], Pp);
    rowfuse_kernel<<<401, 256, 0, stream>>>(
        Pp, PVS, 8, 0, (const float*)d_in[14], 0, h0, nullptr, h0,
        (const float*)d_in[15], (const float*)d_in[16], xln);

    // -------- layer 2: split-K4 K,V (partials), CLS flash-decode ----------
    gemm_split_kernel<<<dim3(7, 16, 4), 256, 0, stream>>>(
        xln, 512, (const float*)d_in[21] + 512, 1536, Pq, 1024, PKS,
        401, 1024, 512, 4);
    cls_decode_kernel<<<dim3(8, 7), 256, 0, stream>>>(
        xln, (const float*)d_in[21], Pq, (const float*)d_in[22],
        pm, pf, T + 8L * TSTRIDE, cms, cpv, cnt);
    cls_proj_kernel<<<8, 256, 0, stream>>>(
        cms, cpv, (const float*)d_in[23], (const float*)d_in[24], proj0,
        h0, (const float*)d_in[25], (const float*)d_in[26],
        (const float*)d_in[27], (const float*)d_in[28], (float*)d_out, cnt);
}